// Round 9
// baseline (5706.137 us; speedup 1.0000x reference)
//
#include <hip/hip_runtime.h>
#include <hip/hip_bf16.h>
#include <cmath>

#define C_IN 128
#define NKEY 32
#define N_H 4
#define D_H 32
#define C_BEV 256
#define H_Y 180
#define W_X 180
#define LDK16 (C_IN + 8)  // padded bf16 LDS stride (136)

typedef __attribute__((ext_vector_type(8))) short short8;

__device__ __forceinline__ float gelu_exact(float x) {
    return 0.5f * x * (1.0f + erff(x * 0.7071067811865475f));
}

__device__ __forceinline__ float dot4(float4 a, float4 b) {
    return a.x * b.x + a.y * b.y + a.z * b.z + a.w * b.w;
}

__device__ __forceinline__ float bf2f(ushort u) {
    union { unsigned int i; float f; } c; c.i = ((unsigned int)u) << 16; return c.f;
}

__device__ __forceinline__ ushort f2bf(float x) {
    __hip_bfloat16 h = __float2bfloat16(x);
    return *reinterpret_cast<ushort*>(&h);
}

// ---- pass 1: inv[cell] = m  (inv pre-memset to -1)
__global__ void build_inv(const int* __restrict__ ni, int* __restrict__ inv, int M) {
    const int m = blockIdx.x * 256 + threadIdx.x;
    if (m < M) {
        const int b = ni[m*4+0], y = ni[m*4+2], x = ni[m*4+3];
        inv[(b * H_Y + y) * W_X + x] = m;
    }
}

// ---- pass 2: compact bev -> bevq[m][256] contiguous
__global__ __launch_bounds__(256) void compact_bev(
    const float* __restrict__ bev, const int* __restrict__ inv,
    float* __restrict__ bevq)
{
    const int bid = blockIdx.x;
    const int xr = bid % 12;
    const int y  = (bid / 12) % H_Y;
    const int b  = bid / (12 * H_Y);
    const int x0 = xr * 16;
    const int width = (x0 + 16 <= W_X) ? 16 : (W_X - x0);   // 16 or 4
    const int tid = threadIdx.x;

    __shared__ float tile[16][257];

    const int xq = (tid & 3) * 4;
    #pragma unroll
    for (int p = 0; p < 4; ++p) {
        const int c = p * 64 + (tid >> 2);
        if (xq < width) {
            const float4 v = *(const float4*)(bev +
                (((size_t)b * C_BEV + c) * H_Y + y) * W_X + x0 + xq);
            tile[xq+0][c] = v.x; tile[xq+1][c] = v.y;
            tile[xq+2][c] = v.z; tile[xq+3][c] = v.w;
        }
    }
    __syncthreads();
    for (int xi = 0; xi < width; ++xi) {
        const int m = inv[(b * H_Y + y) * W_X + x0 + xi];
        if (m >= 0) bevq[(size_t)m * C_BEV + tid] = tile[xi][tid];
    }
}

// ---- pass 4: dense output: out[b,c,y,x] = featbuf[inv[b,y,x]][c] or 0
__global__ __launch_bounds__(256) void write_out(
    const int* __restrict__ inv, const float* __restrict__ featbuf,
    float* __restrict__ out)
{
    const unsigned TOT = 4u * C_IN * H_Y * W_X;
    for (unsigned i = blockIdx.x * 256 + threadIdx.x; i < TOT; i += 2048u * 256u) {
        const unsigned x = i % W_X;
        const unsigned t1 = i / W_X;
        const unsigned y = t1 % H_Y;
        const unsigned t2 = t1 / H_Y;
        const unsigned c = t2 & 127u;
        const unsigned b = t2 >> 7;
        const int m = inv[(b * H_Y + y) * W_X + x];
        out[i] = (m >= 0) ? featbuf[(unsigned)m * C_IN + c] : 0.0f;
    }
}

// ---- pass 3: PERSISTENT fused kernel: grid-stride loop over query pairs.
// Low-rank attention (identical math to R8):
//   logits[h,p] = (t[h]·k[p] + tb[h])*s,  t[h] = qh_h @ wk_h
//   av[h]       = kbar[h] @ wv_h^T + bv,  kbar[h] = sum_p attn[h,p] k[p]
__global__ __launch_bounds__(512) void gridbev_fused(
    const float* __restrict__ vf,        // NV x 128
    const int*   __restrict__ spi,       // NV x 4 (b,z,y,x)
    const int*   __restrict__ ni,        // M x 4 (b,0,y,x)
    const int*   __restrict__ kidx,      // M x 32
    const float* __restrict__ bevq,      // M x 256 (compacted)
    const float* __restrict__ w_pos, const float* __restrict__ b_pos,
    const float* __restrict__ w_bev, const float* __restrict__ b_bev,
    const float* __restrict__ g_q,  const float* __restrict__ be_q,
    const float* __restrict__ g_k,  const float* __restrict__ be_k,
    const float* __restrict__ g_f,  const float* __restrict__ be_f,
    const float* __restrict__ w_in, const float* __restrict__ b_in,
    const float* __restrict__ w_out, const float* __restrict__ b_out,
    const float* __restrict__ w_fc1, const float* __restrict__ b_fc1,
    const float* __restrict__ w_fc2, const float* __restrict__ b_fc2,
    float* __restrict__ featbuf,         // M x 128 (compact out)
    const int M)
{
    const int tid = threadIdx.x;
    const int npairs = (M + 1) >> 1;

    __shared__ __align__(16) char smem[27904];
    ushort (*kf16)[LDK16] = (ushort(*)[LDK16])smem;        // [64][136] bf16
    float* bevf  = (float*)(smem + 17408);   // [2][256]; later xfs[2][128]
    float* xfs   = bevf;
    float* sc    = (float*)(smem + 19456);   // [2][128]; later h1s
    float* h1s   = sc;
    float* qln   = (float*)(smem + 20480);   // [2][128]; later ylns
    float* ylns  = qln;
    float* qhs   = (float*)(smem + 21504);   // [2][128]; later avs
    float* avs   = qhs;
    float* tk    = (float*)(smem + 22528);   // [2][4][128]: t, then kbar
    float* attnw = (float*)(smem + 26624);   // [2][4][32]
    int*   kmsk  = (int*)(smem + 27648);     // [64]

    for (int pair = blockIdx.x; pair < npairs; pair += gridDim.x) {
    const int m2 = pair * 2;
    const int mA = m2;
    const int mB = (m2 + 1 < M) ? (m2 + 1) : (M - 1);
    const int nxA = ni[mA*4+3], nyA = ni[mA*4+2];
    const int nxB = ni[mB*4+3], nyB = ni[mB*4+2];

    // ---- early coalesced gather of compacted bev
    const int qg  = tid >> 8;
    const int cch = tid & 255;
    const float bevreg = bevq[(size_t)(qg ? mB : mA) * C_BEV + cch];

    // ---- P1: 64 key rows x 8 threads: gather + posemb GELU + LN_k -> kf16
    {
        const int kk = tid >> 3;          // 0..63 (key slot; query = kk>>5)
        const int qk = kk >> 5;
        const int g  = tid & 7;
        const int c0 = g * 16;
        const int mq = qk ? mB : mA;
        const int nxk = qk ? nxB : nxA, nyk = qk ? nyB : nyA;
        const float qxk = (nxk + 0.5f) * (150.4f / 180.0f) - 75.2f;
        const float qyk = (nyk + 0.5f) * (150.4f / 180.0f) - 75.2f;

        const int kv = kidx[mq * NKEY + (kk & 31)];
        if (g == 0) kmsk[kk] = (kv < 0) ? 1 : 0;
        const int safe = (kv < 0) ? 0 : kv;
        const int sz = spi[safe * 4 + 1];
        const int sy = spi[safe * 4 + 2];
        const int sx = spi[safe * 4 + 3];
        const float cx = (sx + 0.5f) * (150.4f / 1440.0f) - 75.2f - qxk;
        const float cy = (sy + 0.5f) * (150.4f / 1440.0f) - 75.2f - qyk;
        const float cz = (sz + 0.5f) * (6.0f / 40.0f)     - 2.0f  - 1.0f;

        float v[16];
        const float4* src = (const float4*)(vf + (size_t)safe * C_IN + c0);
        #pragma unroll
        for (int j = 0; j < 4; ++j) {
            float4 t = src[j];
            v[j*4+0] = t.x; v[j*4+1] = t.y; v[j*4+2] = t.z; v[j*4+3] = t.w;
        }
        #pragma unroll
        for (int j = 0; j < 16; ++j) {
            const int c = c0 + j;
            float e = cx * w_pos[c*3+0] + cy * w_pos[c*3+1] + cz * w_pos[c*3+2] + b_pos[c];
            v[j] += gelu_exact(e);
        }
        float s = 0.f;
        #pragma unroll
        for (int j = 0; j < 16; ++j) s += v[j];
        s += __shfl_xor(s, 1); s += __shfl_xor(s, 2); s += __shfl_xor(s, 4);
        const float mean = s * (1.0f / 128.0f);
        float vv = 0.f;
        #pragma unroll
        for (int j = 0; j < 16; ++j) { float d = v[j] - mean; vv += d * d; }
        vv += __shfl_xor(vv, 1); vv += __shfl_xor(vv, 2); vv += __shfl_xor(vv, 4);
        const float rs = rsqrtf(vv * (1.0f / 128.0f) + 1e-5f);
        ushort o[16];
        #pragma unroll
        for (int j = 0; j < 16; ++j) {
            const int c = c0 + j;
            o[j] = f2bf((v[j] - mean) * rs * g_k[c] + be_k[c]);
        }
        short8* drow = (short8*)(&kf16[kk][c0]);
        drow[0] = *(short8*)&o[0];
        drow[1] = *(short8*)&o[8];
    }

    bevf[qg * 256 + cch] = bevreg;
    __syncthreads();                                   // b1

    // ---- shortcut = gelu(bev @ w_bev^T + b_bev)   (2 thr / output ch)
    {
        const int q = tid >> 8, c = (tid >> 1) & 127, half = tid & 1;
        const float4* wr = (const float4*)(w_bev + (size_t)c * C_BEV + half * 128);
        const float4* br = (const float4*)(&bevf[q * 256 + half * 128]);
        float acc = 0.f;
        #pragma unroll
        for (int k = 0; k < 32; ++k) acc += dot4(wr[k], br[k]);
        acc += __shfl_xor(acc, 1);
        if (half == 0) sc[q * 128 + c] = gelu_exact(acc + b_bev[c]);
    }
    __syncthreads();                                   // b2

    // ---- q = LN(shortcut)
    {
        const int q = tid >> 8, lane = tid & 63;
        const float v0 = sc[q*128 + lane], v1 = sc[q*128 + lane + 64];
        float s = v0 + v1;
        #pragma unroll
        for (int o = 32; o >= 1; o >>= 1) s += __shfl_xor(s, o);
        const float mean = s * (1.0f / 128.0f);
        const float d0 = v0 - mean, d1 = v1 - mean;
        float vv = d0 * d0 + d1 * d1;
        #pragma unroll
        for (int o = 32; o >= 1; o >>= 1) vv += __shfl_xor(vv, o);
        const float rs = rsqrtf(vv * (1.0f / 128.0f) + 1e-5f);
        if ((tid & 255) < 128) {
            const int idx = tid & 127;
            const float myv = (idx < 64) ? v0 : v1;
            qln[q*128 + idx] = (myv - mean) * rs * g_q[idx] + be_q[idx];
        }
    }
    __syncthreads();                                   // b3

    // ---- qh = qln @ wq^T + bq
    {
        const int q = tid >> 8, c = (tid >> 1) & 127, half = tid & 1;
        const float4* wr = (const float4*)(w_in + (size_t)c * C_IN + half * 64);
        const float4* qr = (const float4*)(&qln[q*128 + half * 64]);
        float acc = 0.f;
        #pragma unroll
        for (int k = 0; k < 16; ++k) acc += dot4(wr[k], qr[k]);
        acc += __shfl_xor(acc, 1);
        if (half == 0) qhs[q*128 + c] = acc + b_in[c];
    }
    __syncthreads();                                   // b4

    // ---- t[h] = qh_h @ wk_h  (4x128 per query; 2 h's per thread)
    {
        const int q = tid >> 8, r = tid & 255;
        const int c = r & 127, h2 = r >> 7;
        #pragma unroll
        for (int hi = 0; hi < 2; ++hi) {
            const int hh = h2 + 2 * hi;
            float acc = 0.f;
            #pragma unroll
            for (int d = 0; d < D_H; ++d)
                acc += qhs[q*128 + hh*D_H + d] * w_in[(size_t)(C_IN + hh*D_H + d) * C_IN + c];
            tk[(q*4 + hh)*128 + c] = acc;
        }
    }
    __syncthreads();                                   // b5

    // ---- logits + masked softmax: (q,h,p) per thread (tid<256)
    if (tid < 256) {
        const int q = tid >> 7, h = (tid >> 5) & 3, p = tid & 31;
        float tbv = qhs[q*128 + h*D_H + p] * b_in[C_IN + h*D_H + p];
        #pragma unroll
        for (int o = 16; o >= 1; o >>= 1) tbv += __shfl_xor(tbv, o);
        const float* tr = &tk[(q*4 + h)*128];
        const ushort* kr = kf16[q*NKEY + p];
        float d = 0.f;
        #pragma unroll
        for (int c2 = 0; c2 < 64; ++c2) {
            const uint u = *(const uint*)&kr[c2*2];
            d += tr[c2*2]   * bf2f((ushort)(u & 0xffff));
            d += tr[c2*2+1] * bf2f((ushort)(u >> 16));
        }
        const int msk = kmsk[q*NKEY + p];
        float logit = msk ? -3.0e38f : (d + tbv) * 0.17677669529663687f;
        float mx = logit;
        #pragma unroll
        for (int o = 16; o >= 1; o >>= 1) mx = fmaxf(mx, __shfl_xor(mx, o));
        const float e = msk ? 0.0f : expf(logit - mx);
        float ssum = e;
        #pragma unroll
        for (int o = 16; o >= 1; o >>= 1) ssum += __shfl_xor(ssum, o);
        attnw[(q*4 + h)*32 + p] = e / ssum;
    }
    __syncthreads();                                   // b6

    // ---- kbar[h] = sum_p attn[h,p] * k[p]  (overwrites tk)
    {
        const int q = tid >> 8, r = tid & 255;
        const int c = r & 127, h2 = r >> 7;
        #pragma unroll
        for (int hi = 0; hi < 2; ++hi) {
            const int hh = h2 + 2 * hi;
            float acc = 0.f;
            #pragma unroll
            for (int p = 0; p < NKEY; ++p)
                acc += attnw[(q*4 + hh)*32 + p] * bf2f(kf16[q*NKEY + p][c]);
            tk[(q*4 + hh)*128 + c] = acc;
        }
    }
    __syncthreads();                                   // b7

    // ---- av[j] = kbar[h(j)] . wv_row(j) + bv[j]   (2 thr / output)
    {
        const int q = tid >> 8, j = (tid >> 1) & 127, half = tid & 1;
        const int h = j >> 5;
        const float4* wr = (const float4*)(w_in + (size_t)(2*C_IN + j) * C_IN + half * 64);
        const float4* kb = (const float4*)(&tk[(q*4 + h)*128 + half * 64]);
        float acc = 0.f;
        #pragma unroll
        for (int k = 0; k < 16; ++k) acc += dot4(wr[k], kb[k]);
        acc += __shfl_xor(acc, 1);
        if (half == 0) avs[q*128 + j] = acc + b_in[2*C_IN + j];
    }
    __syncthreads();                                   // b8

    // ---- attend = av @ w_out^T + b_out; xf = attend + shortcut
    {
        const int q = tid >> 8, c = (tid >> 1) & 127, half = tid & 1;
        const float4* wr = (const float4*)(w_out + (size_t)c * C_IN + half * 64);
        const float4* ar = (const float4*)(&avs[q*128 + half * 64]);
        float acc = 0.f;
        #pragma unroll
        for (int k = 0; k < 16; ++k) acc += dot4(wr[k], ar[k]);
        acc += __shfl_xor(acc, 1);
        if (half == 0) xfs[q*128 + c] = acc + b_out[c] + sc[q*128 + c];
    }
    __syncthreads();                                   // b9

    // ---- LN(xf) -> ylns
    {
        const int q = tid >> 8, lane = tid & 63;
        const float v0 = xfs[q*128 + lane], v1 = xfs[q*128 + lane + 64];
        float s = v0 + v1;
        #pragma unroll
        for (int o = 32; o >= 1; o >>= 1) s += __shfl_xor(s, o);
        const float mean = s * (1.0f / 128.0f);
        const float d0 = v0 - mean, d1 = v1 - mean;
        float vv = d0 * d0 + d1 * d1;
        #pragma unroll
        for (int o = 32; o >= 1; o >>= 1) vv += __shfl_xor(vv, o);
        const float rs = rsqrtf(vv * (1.0f / 128.0f) + 1e-5f);
        if ((tid & 255) < 128) {
            const int idx = tid & 127;
            const float myv = (idx < 64) ? v0 : v1;
            ylns[q*128 + idx] = (myv - mean) * rs * g_f[idx] + be_f[idx];
        }
    }
    __syncthreads();                                   // b10

    // ---- fc1
    {
        const int q = tid >> 8, c = (tid >> 1) & 127, half = tid & 1;
        const float4* wr = (const float4*)(w_fc1 + (size_t)c * C_IN + half * 64);
        const float4* yr = (const float4*)(&ylns[q*128 + half * 64]);
        float acc = 0.f;
        #pragma unroll
        for (int k = 0; k < 16; ++k) acc += dot4(wr[k], yr[k]);
        acc += __shfl_xor(acc, 1);
        if (half == 0) h1s[q*128 + c] = gelu_exact(acc + b_fc1[c]);
    }
    __syncthreads();                                   // b11

    // ---- fc2 + residual -> compact featbuf (coalesced)
    {
        const int q = tid >> 8, c = (tid >> 1) & 127, half = tid & 1;
        const float4* wr = (const float4*)(w_fc2 + (size_t)c * C_IN + half * 64);
        const float4* hr = (const float4*)(&h1s[q*128 + half * 64]);
        float acc = 0.f;
        #pragma unroll
        for (int k = 0; k < 16; ++k) acc += dot4(wr[k], hr[k]);
        acc += __shfl_xor(acc, 1);
        if (half == 0 && (m2 + q) < M) {
            featbuf[(size_t)(m2 + q) * C_IN + c] = acc + b_fc2[c] + xfs[q*128 + c];
        }
    }
    __syncthreads();                                   // b12 (loop-carried LDS safety)
    }  // persistent loop
}

extern "C" void kernel_launch(void* const* d_in, const int* in_sizes, int n_in,
                              void* d_out, int out_size, void* d_ws, size_t ws_size,
                              hipStream_t stream) {
    const float* vf    = (const float*)d_in[0];
    const int*   spi   = (const int*)  d_in[1];
    const int*   ni    = (const int*)  d_in[2];
    const int*   kidx  = (const int*)  d_in[3];
    const float* bev   = (const float*)d_in[4];
    const float* w_pos = (const float*)d_in[5];
    const float* b_pos = (const float*)d_in[6];
    const float* w_bev = (const float*)d_in[7];
    const float* b_bev = (const float*)d_in[8];
    const float* g_q   = (const float*)d_in[9];
    const float* be_q  = (const float*)d_in[10];
    const float* g_k   = (const float*)d_in[11];
    const float* be_k  = (const float*)d_in[12];
    const float* g_f   = (const float*)d_in[13];
    const float* be_f  = (const float*)d_in[14];
    const float* w_in  = (const float*)d_in[15];
    const float* b_in  = (const float*)d_in[16];
    const float* w_out = (const float*)d_in[17];
    const float* b_out = (const float*)d_in[18];
    const float* w_fc1 = (const float*)d_in[19];
    const float* b_fc1 = (const float*)d_in[20];
    const float* w_fc2 = (const float*)d_in[21];
    const float* b_fc2 = (const float*)d_in[22];
    float* out = (float*)d_out;

    const int M = in_sizes[3] / NKEY;

    // ---- workspace layout (needs ~49 MB)
    char* ws = (char*)d_ws;
    int*   inv     = (int*)ws;                          // 518400 ints
    float* bevq    = (float*)(ws + (2u << 20));         // M x 256 floats (30.7 MB)
    float* featbuf = (float*)(ws + (33u << 20));        // M x 128 floats (15.4 MB)

    hipMemsetAsync(inv, 0xFF, (size_t)4 * H_Y * W_X * sizeof(int), stream);
    build_inv<<<(M + 255) / 256, 256, 0, stream>>>(ni, inv, M);
    compact_bev<<<4 * H_Y * 12, 256, 0, stream>>>(bev, inv, bevq);

    const int npairs = (M + 1) / 2;
    const int nblk = npairs < 1024 ? npairs : 1024;
    gridbev_fused<<<nblk, 512, 0, stream>>>(
        vf, spi, ni, kidx, bevq, w_pos, b_pos, w_bev, b_bev,
        g_q, be_q, g_k, be_k, g_f, be_f, w_in, b_in,
        w_out, b_out, w_fc1, b_fc1, w_fc2, b_fc2, featbuf, M);

    write_out<<<2048, 256, 0, stream>>>(inv, featbuf, out);
}

// Round 12
// 5350.193 us; speedup vs baseline: 1.0665x; 1.0665x over previous
//
#include <hip/hip_runtime.h>
#include <hip/hip_bf16.h>
#include <cmath>

#define C_IN 128
#define NKEY 32
#define N_H 4
#define D_H 32
#define C_BEV 256
#define H_Y 180
#define W_X 180
#define LDK16 (C_IN + 8)  // padded bf16 LDS stride (136)

typedef __attribute__((ext_vector_type(8))) short short8;

__device__ __forceinline__ float gelu_exact(float x) {
    return 0.5f * x * (1.0f + erff(x * 0.7071067811865475f));
}

__device__ __forceinline__ float dot4(float4 a, float4 b) {
    return a.x * b.x + a.y * b.y + a.z * b.z + a.w * b.w;
}

__device__ __forceinline__ float bf2f(ushort u) {
    union { unsigned int i; float f; } c; c.i = ((unsigned int)u) << 16; return c.f;
}

__device__ __forceinline__ ushort f2bf(float x) {
    __hip_bfloat16 h = __float2bfloat16(x);
    return *reinterpret_cast<ushort*>(&h);
}

// ---- pass 1: inv[cell] = m  (inv pre-memset to -1)
__global__ void build_inv(const int* __restrict__ ni, int* __restrict__ inv, int M) {
    const int m = blockIdx.x * 256 + threadIdx.x;
    if (m < M) {
        const int b = ni[m*4+0], y = ni[m*4+2], x = ni[m*4+3];
        inv[(b * H_Y + y) * W_X + x] = m;
    }
}

// ---- pass 2: compact bev -> bevq[m][256] contiguous
__global__ __launch_bounds__(256) void compact_bev(
    const float* __restrict__ bev, const int* __restrict__ inv,
    float* __restrict__ bevq)
{
    const int bid = blockIdx.x;
    const int xr = bid % 12;
    const int y  = (bid / 12) % H_Y;
    const int b  = bid / (12 * H_Y);
    const int x0 = xr * 16;
    const int width = (x0 + 16 <= W_X) ? 16 : (W_X - x0);   // 16 or 4
    const int tid = threadIdx.x;

    __shared__ float tile[16][257];

    const int xq = (tid & 3) * 4;
    #pragma unroll
    for (int p = 0; p < 4; ++p) {
        const int c = p * 64 + (tid >> 2);
        if (xq < width) {
            const float4 v = *(const float4*)(bev +
                (((size_t)b * C_BEV + c) * H_Y + y) * W_X + x0 + xq);
            tile[xq+0][c] = v.x; tile[xq+1][c] = v.y;
            tile[xq+2][c] = v.z; tile[xq+3][c] = v.w;
        }
    }
    __syncthreads();
    for (int xi = 0; xi < width; ++xi) {
        const int m = inv[(b * H_Y + y) * W_X + x0 + xi];
        if (m >= 0) bevq[(size_t)m * C_BEV + tid] = tile[xi][tid];
    }
}

// ---- pass 4: dense output: out[b,c,y,x] = featbuf[inv[b,y,x]][c] or 0
__global__ __launch_bounds__(256) void write_out(
    const int* __restrict__ inv, const float* __restrict__ featbuf,
    float* __restrict__ out)
{
    const unsigned TOT = 4u * C_IN * H_Y * W_X;
    for (unsigned i = blockIdx.x * 256 + threadIdx.x; i < TOT; i += 2048u * 256u) {
        const unsigned x = i % W_X;
        const unsigned t1 = i / W_X;
        const unsigned y = t1 % H_Y;
        const unsigned t2 = t1 / H_Y;
        const unsigned c = t2 & 127u;
        const unsigned b = t2 >> 7;
        const int m = inv[(b * H_Y + y) * W_X + x];
        out[i] = (m >= 0) ? featbuf[(unsigned)m * C_IN + c] : 0.0f;
    }
}

// ---- pass 3: PERSISTENT fused kernel: grid-stride loop over query pairs.
// __launch_bounds__(512,4) pins VGPR<=64 (R9 without it spilled: 8GB scratch).
__global__ __launch_bounds__(512, 4) void gridbev_fused(
    const float* __restrict__ vf,        // NV x 128
    const int*   __restrict__ spi,       // NV x 4 (b,z,y,x)
    const int*   __restrict__ ni,        // M x 4 (b,0,y,x)
    const int*   __restrict__ kidx,      // M x 32
    const float* __restrict__ bevq,      // M x 256 (compacted)
    const float* __restrict__ w_pos, const float* __restrict__ b_pos,
    const float* __restrict__ w_bev, const float* __restrict__ b_bev,
    const float* __restrict__ g_q,  const float* __restrict__ be_q,
    const float* __restrict__ g_k,  const float* __restrict__ be_k,
    const float* __restrict__ g_f,  const float* __restrict__ be_f,
    const float* __restrict__ w_in, const float* __restrict__ b_in,
    const float* __restrict__ w_out, const float* __restrict__ b_out,
    const float* __restrict__ w_fc1, const float* __restrict__ b_fc1,
    const float* __restrict__ w_fc2, const float* __restrict__ b_fc2,
    float* __restrict__ featbuf,         // M x 128 (compact out)
    const int M)
{
    const int tid = threadIdx.x;
    const int npairs = (M + 1) >> 1;

    __shared__ __align__(16) char smem[27904];
    ushort (*kf16)[LDK16] = (ushort(*)[LDK16])smem;        // [64][136] bf16
    float* bevf  = (float*)(smem + 17408);   // [2][256]; later xfs[2][128]
    float* xfs   = bevf;
    float* sc    = (float*)(smem + 19456);   // [2][128]; later h1s
    float* h1s   = sc;
    float* qln   = (float*)(smem + 20480);   // [2][128]; later ylns
    float* ylns  = qln;
    float* qhs   = (float*)(smem + 21504);   // [2][128]; later avs
    float* avs   = qhs;
    float* tk    = (float*)(smem + 22528);   // [2][4][128]: t, then kbar
    float* attnw = (float*)(smem + 26624);   // [2][4][32]
    int*   kmsk  = (int*)(smem + 27648);     // [64]

    for (int pair = blockIdx.x; pair < npairs; pair += gridDim.x) {
    const int m2 = pair * 2;
    const int mA = m2;
    const int mB = (m2 + 1 < M) ? (m2 + 1) : (M - 1);
    const int nxA = ni[mA*4+3], nyA = ni[mA*4+2];
    const int nxB = ni[mB*4+3], nyB = ni[mB*4+2];

    // ---- early coalesced gather of compacted bev
    const int qg  = tid >> 8;
    const int cch = tid & 255;
    const float bevreg = bevq[(size_t)(qg ? mB : mA) * C_BEV + cch];

    // ---- P1: 64 key rows x 8 threads: gather + posemb GELU + LN_k -> kf16
    {
        const int kk = tid >> 3;          // 0..63 (key slot; query = kk>>5)
        const int qk = kk >> 5;
        const int g  = tid & 7;
        const int c0 = g * 16;
        const int mq = qk ? mB : mA;
        const int nxk = qk ? nxB : nxA, nyk = qk ? nyB : nyA;
        const float qxk = (nxk + 0.5f) * (150.4f / 180.0f) - 75.2f;
        const float qyk = (nyk + 0.5f) * (150.4f / 180.0f) - 75.2f;

        const int kv = kidx[mq * NKEY + (kk & 31)];
        if (g == 0) kmsk[kk] = (kv < 0) ? 1 : 0;
        const int safe = (kv < 0) ? 0 : kv;
        const int sz = spi[safe * 4 + 1];
        const int sy = spi[safe * 4 + 2];
        const int sx = spi[safe * 4 + 3];
        const float cx = (sx + 0.5f) * (150.4f / 1440.0f) - 75.2f - qxk;
        const float cy = (sy + 0.5f) * (150.4f / 1440.0f) - 75.2f - qyk;
        const float cz = (sz + 0.5f) * (6.0f / 40.0f)     - 2.0f  - 1.0f;

        float v[16];
        const float4* src = (const float4*)(vf + (size_t)safe * C_IN + c0);
        #pragma unroll
        for (int j = 0; j < 4; ++j) {
            float4 t = src[j];
            v[j*4+0] = t.x; v[j*4+1] = t.y; v[j*4+2] = t.z; v[j*4+3] = t.w;
        }
        #pragma unroll
        for (int j = 0; j < 16; ++j) {
            const int c = c0 + j;
            float e = cx * w_pos[c*3+0] + cy * w_pos[c*3+1] + cz * w_pos[c*3+2] + b_pos[c];
            v[j] += gelu_exact(e);
        }
        float s = 0.f;
        #pragma unroll
        for (int j = 0; j < 16; ++j) s += v[j];
        s += __shfl_xor(s, 1); s += __shfl_xor(s, 2); s += __shfl_xor(s, 4);
        const float mean = s * (1.0f / 128.0f);
        float vv = 0.f;
        #pragma unroll
        for (int j = 0; j < 16; ++j) { float d = v[j] - mean; vv += d * d; }
        vv += __shfl_xor(vv, 1); vv += __shfl_xor(vv, 2); vv += __shfl_xor(vv, 4);
        const float rs = rsqrtf(vv * (1.0f / 128.0f) + 1e-5f);
        ushort o[16];
        #pragma unroll
        for (int j = 0; j < 16; ++j) {
            const int c = c0 + j;
            o[j] = f2bf((v[j] - mean) * rs * g_k[c] + be_k[c]);
        }
        short8* drow = (short8*)(&kf16[kk][c0]);
        drow[0] = *(short8*)&o[0];
        drow[1] = *(short8*)&o[8];
    }

    bevf[qg * 256 + cch] = bevreg;
    __syncthreads();                                   // b1

    // ---- shortcut = gelu(bev @ w_bev^T + b_bev)   (2 thr / output ch)
    {
        const int q = tid >> 8, c = (tid >> 1) & 127, half = tid & 1;
        const float4* wr = (const float4*)(w_bev + (size_t)c * C_BEV + half * 128);
        const float4* br = (const float4*)(&bevf[q * 256 + half * 128]);
        float acc = 0.f;
        #pragma unroll
        for (int k = 0; k < 32; ++k) acc += dot4(wr[k], br[k]);
        acc += __shfl_xor(acc, 1);
        if (half == 0) sc[q * 128 + c] = gelu_exact(acc + b_bev[c]);
    }
    __syncthreads();                                   // b2

    // ---- q = LN(shortcut)
    {
        const int q = tid >> 8, lane = tid & 63;
        const float v0 = sc[q*128 + lane], v1 = sc[q*128 + lane + 64];
        float s = v0 + v1;
        #pragma unroll
        for (int o = 32; o >= 1; o >>= 1) s += __shfl_xor(s, o);
        const float mean = s * (1.0f / 128.0f);
        const float d0 = v0 - mean, d1 = v1 - mean;
        float vv = d0 * d0 + d1 * d1;
        #pragma unroll
        for (int o = 32; o >= 1; o >>= 1) vv += __shfl_xor(vv, o);
        const float rs = rsqrtf(vv * (1.0f / 128.0f) + 1e-5f);
        if ((tid & 255) < 128) {
            const int idx = tid & 127;
            const float myv = (idx < 64) ? v0 : v1;
            qln[q*128 + idx] = (myv - mean) * rs * g_q[idx] + be_q[idx];
        }
    }
    __syncthreads();                                   // b3

    // ---- qh = qln @ wq^T + bq
    {
        const int q = tid >> 8, c = (tid >> 1) & 127, half = tid & 1;
        const float4* wr = (const float4*)(w_in + (size_t)c * C_IN + half * 64);
        const float4* qr = (const float4*)(&qln[q*128 + half * 64]);
        float acc = 0.f;
        #pragma unroll
        for (int k = 0; k < 16; ++k) acc += dot4(wr[k], qr[k]);
        acc += __shfl_xor(acc, 1);
        if (half == 0) qhs[q*128 + c] = acc + b_in[c];
    }
    __syncthreads();                                   // b4

    // ---- t[h] = qh_h @ wk_h  (4x128 per query; 2 h's per thread)
    {
        const int q = tid >> 8, r = tid & 255;
        const int c = r & 127, h2 = r >> 7;
        #pragma unroll
        for (int hi = 0; hi < 2; ++hi) {
            const int hh = h2 + 2 * hi;
            float acc = 0.f;
            #pragma unroll
            for (int d = 0; d < D_H; ++d)
                acc += qhs[q*128 + hh*D_H + d] * w_in[(size_t)(C_IN + hh*D_H + d) * C_IN + c];
            tk[(q*4 + hh)*128 + c] = acc;
        }
    }
    __syncthreads();                                   // b5

    // ---- logits + masked softmax: (q,h,p) per thread (tid<256)
    if (tid < 256) {
        const int q = tid >> 7, h = (tid >> 5) & 3, p = tid & 31;
        float tbv = qhs[q*128 + h*D_H + p] * b_in[C_IN + h*D_H + p];
        #pragma unroll
        for (int o = 16; o >= 1; o >>= 1) tbv += __shfl_xor(tbv, o);
        const float* tr = &tk[(q*4 + h)*128];
        const ushort* kr = kf16[q*NKEY + p];
        float d = 0.f;
        #pragma unroll
        for (int c2 = 0; c2 < 64; ++c2) {
            const uint u = *(const uint*)&kr[c2*2];
            d += tr[c2*2]   * bf2f((ushort)(u & 0xffff));
            d += tr[c2*2+1] * bf2f((ushort)(u >> 16));
        }
        const int msk = kmsk[q*NKEY + p];
        float logit = msk ? -3.0e38f : (d + tbv) * 0.17677669529663687f;
        float mx = logit;
        #pragma unroll
        for (int o = 16; o >= 1; o >>= 1) mx = fmaxf(mx, __shfl_xor(mx, o));
        const float e = msk ? 0.0f : expf(logit - mx);
        float ssum = e;
        #pragma unroll
        for (int o = 16; o >= 1; o >>= 1) ssum += __shfl_xor(ssum, o);
        attnw[(q*4 + h)*32 + p] = e / ssum;
    }
    __syncthreads();                                   // b6

    // ---- kbar[h] = sum_p attn[h,p] * k[p]  (overwrites tk)
    {
        const int q = tid >> 8, r = tid & 255;
        const int c = r & 127, h2 = r >> 7;
        #pragma unroll
        for (int hi = 0; hi < 2; ++hi) {
            const int hh = h2 + 2 * hi;
            float acc = 0.f;
            #pragma unroll
            for (int p = 0; p < NKEY; ++p)
                acc += attnw[(q*4 + hh)*32 + p] * bf2f(kf16[q*NKEY + p][c]);
            tk[(q*4 + hh)*128 + c] = acc;
        }
    }
    __syncthreads();                                   // b7

    // ---- av[j] = kbar[h(j)] . wv_row(j) + bv[j]   (2 thr / output)
    {
        const int q = tid >> 8, j = (tid >> 1) & 127, half = tid & 1;
        const int h = j >> 5;
        const float4* wr = (const float4*)(w_in + (size_t)(2*C_IN + j) * C_IN + half * 64);
        const float4* kb = (const float4*)(&tk[(q*4 + h)*128 + half * 64]);
        float acc = 0.f;
        #pragma unroll
        for (int k = 0; k < 16; ++k) acc += dot4(wr[k], kb[k]);
        acc += __shfl_xor(acc, 1);
        if (half == 0) avs[q*128 + j] = acc + b_in[2*C_IN + j];
    }
    __syncthreads();                                   // b8

    // ---- attend = av @ w_out^T + b_out; xf = attend + shortcut
    {
        const int q = tid >> 8, c = (tid >> 1) & 127, half = tid & 1;
        const float4* wr = (const float4*)(w_out + (size_t)c * C_IN + half * 64);
        const float4* ar = (const float4*)(&avs[q*128 + half * 64]);
        float acc = 0.f;
        #pragma unroll
        for (int k = 0; k < 16; ++k) acc += dot4(wr[k], ar[k]);
        acc += __shfl_xor(acc, 1);
        if (half == 0) xfs[q*128 + c] = acc + b_out[c] + sc[q*128 + c];
    }
    __syncthreads();                                   // b9

    // ---- LN(xf) -> ylns
    {
        const int q = tid >> 8, lane = tid & 63;
        const float v0 = xfs[q*128 + lane], v1 = xfs[q*128 + lane + 64];
        float s = v0 + v1;
        #pragma unroll
        for (int o = 32; o >= 1; o >>= 1) s += __shfl_xor(s, o);
        const float mean = s * (1.0f / 128.0f);
        const float d0 = v0 - mean, d1 = v1 - mean;
        float vv = d0 * d0 + d1 * d1;
        #pragma unroll
        for (int o = 32; o >= 1; o >>= 1) vv += __shfl_xor(vv, o);
        const float rs = rsqrtf(vv * (1.0f / 128.0f) + 1e-5f);
        if ((tid & 255) < 128) {
            const int idx = tid & 127;
            const float myv = (idx < 64) ? v0 : v1;
            ylns[q*128 + idx] = (myv - mean) * rs * g_f[idx] + be_f[idx];
        }
    }
    __syncthreads();                                   // b10

    // ---- fc1
    {
        const int q = tid >> 8, c = (tid >> 1) & 127, half = tid & 1;
        const float4* wr = (const float4*)(w_fc1 + (size_t)c * C_IN + half * 64);
        const float4* yr = (const float4*)(&ylns[q*128 + half * 64]);
        float acc = 0.f;
        #pragma unroll
        for (int k = 0; k < 16; ++k) acc += dot4(wr[k], yr[k]);
        acc += __shfl_xor(acc, 1);
        if (half == 0) h1s[q*128 + c] = gelu_exact(acc + b_fc1[c]);
    }
    __syncthreads();                                   // b11

    // ---- fc2 + residual -> compact featbuf (coalesced)
    {
        const int q = tid >> 8, c = (tid >> 1) & 127, half = tid & 1;
        const float4* wr = (const float4*)(w_fc2 + (size_t)c * C_IN + half * 64);
        const float4* hr = (const float4*)(&h1s[q*128 + half * 64]);
        float acc = 0.f;
        #pragma unroll
        for (int k = 0; k < 16; ++k) acc += dot4(wr[k], hr[k]);
        acc += __shfl_xor(acc, 1);
        if (half == 0 && (m2 + q) < M) {
            featbuf[(size_t)(m2 + q) * C_IN + c] = acc + b_fc2[c] + xfs[q*128 + c];
        }
    }
    __syncthreads();                                   // b12 (loop-carried LDS safety)
    }  // persistent loop
}

extern "C" void kernel_launch(void* const* d_in, const int* in_sizes, int n_in,
                              void* d_out, int out_size, void* d_ws, size_t ws_size,
                              hipStream_t stream) {
    const float* vf    = (const float*)d_in[0];
    const int*   spi   = (const int*)  d_in[1];
    const int*   ni    = (const int*)  d_in[2];
    const int*   kidx  = (const int*)  d_in[3];
    const float* bev   = (const float*)d_in[4];
    const float* w_pos = (const float*)d_in[5];
    const float* b_pos = (const float*)d_in[6];
    const float* w_bev = (const float*)d_in[7];
    const float* b_bev = (const float*)d_in[8];
    const float* g_q   = (const float*)d_in[9];
    const float* be_q  = (const float*)d_in[10];
    const float* g_k   = (const float*)d_in[11];
    const float* be_k  = (const float*)d_in[12];
    const float* g_f   = (const float*)d_in[13];
    const float* be_f  = (const float*)d_in[14];
    const float* w_in  = (const float*)d_in[15];
    const float* b_in  = (const float*)d_in[16];
    const float* w_out = (const float*)d_in[17];
    const float* b_out = (const float*)d_in[18];
    const float* w_fc1 = (const float*)d_in[19];
    const float* b_fc1 = (const float*)d_in[20];
    const float* w_fc2 = (const float*)d_in[21];
    const float* b_fc2 = (const float*)d_in[22];
    float* out = (float*)d_out;

    const int M = in_sizes[3] / NKEY;

    // ---- workspace layout (needs ~49 MB)
    char* ws = (char*)d_ws;
    int*   inv     = (int*)ws;                          // 518400 ints
    float* bevq    = (float*)(ws + (2u << 20));         // M x 256 floats (30.7 MB)
    float* featbuf = (float*)(ws + (33u << 20));        // M x 128 floats (15.4 MB)

    hipMemsetAsync(inv, 0xFF, (size_t)4 * H_Y * W_X * sizeof(int), stream);
    build_inv<<<(M + 255) / 256, 256, 0, stream>>>(ni, inv, M);
    compact_bev<<<4 * H_Y * 12, 256, 0, stream>>>(bev, inv, bevq);

    const int npairs = (M + 1) / 2;
    const int nblk = npairs < 1024 ? npairs : 1024;
    gridbev_fused<<<nblk, 512, 0, stream>>>(
        vf, spi, ni, kidx, bevq, w_pos, b_pos, w_bev, b_bev,
        g_q, be_q, g_k, be_k, g_f, be_f, w_in, b_in,
        w_out, b_out, w_fc1, b_fc1, w_fc2, b_fc2, featbuf, M);

    write_out<<<2048, 256, 0, stream>>>(inv, featbuf, out);
}

// Round 13
// 2084.759 us; speedup vs baseline: 2.7371x; 2.5663x over previous
//
#include <hip/hip_runtime.h>
#include <hip/hip_bf16.h>
#include <cmath>

#define C_IN 128
#define NKEY 32
#define N_H 4
#define D_H 32
#define C_BEV 256
#define H_Y 180
#define W_X 180

typedef __attribute__((ext_vector_type(8))) short short8;

__device__ __forceinline__ float gelu_exact(float x) {
    return 0.5f * x * (1.0f + erff(x * 0.7071067811865475f));
}
__device__ __forceinline__ float dot4(float4 a, float4 b) {
    return a.x * b.x + a.y * b.y + a.z * b.z + a.w * b.w;
}
__device__ __forceinline__ float bf2f(ushort u) {
    union { unsigned int i; float f; } c; c.i = ((unsigned int)u) << 16; return c.f;
}
__device__ __forceinline__ ushort f2bf(float x) {
    __hip_bfloat16 h = __float2bfloat16(x);
    return *reinterpret_cast<ushort*>(&h);
}

// ---- inv[cell] = m  (inv pre-memset to -1)
__global__ void build_inv(const int* __restrict__ ni, int* __restrict__ inv, int M) {
    const int m = blockIdx.x * 256 + threadIdx.x;
    if (m < M) {
        const int b = ni[m*4+0], y = ni[m*4+2], x = ni[m*4+3];
        inv[(b * H_Y + y) * W_X + x] = m;
    }
}

// ---- compact bev -> bevq[m][256] contiguous (verified R8)
__global__ __launch_bounds__(256) void compact_bev(
    const float* __restrict__ bev, const int* __restrict__ inv,
    float* __restrict__ bevq)
{
    const int bid = blockIdx.x;
    const int xr = bid % 12;
    const int y  = (bid / 12) % H_Y;
    const int b  = bid / (12 * H_Y);
    const int x0 = xr * 16;
    const int width = (x0 + 16 <= W_X) ? 16 : (W_X - x0);
    const int tid = threadIdx.x;

    __shared__ float tile[16][257];

    const int xq = (tid & 3) * 4;
    #pragma unroll
    for (int p = 0; p < 4; ++p) {
        const int c = p * 64 + (tid >> 2);
        if (xq < width) {
            const float4 v = *(const float4*)(bev +
                (((size_t)b * C_BEV + c) * H_Y + y) * W_X + x0 + xq);
            tile[xq+0][c] = v.x; tile[xq+1][c] = v.y;
            tile[xq+2][c] = v.z; tile[xq+3][c] = v.w;
        }
    }
    __syncthreads();
    for (int xi = 0; xi < width; ++xi) {
        const int m = inv[(b * H_Y + y) * W_X + x0 + xi];
        if (m >= 0) bevq[(size_t)m * C_BEV + tid] = tile[xi][tid];
    }
}

// ---- out[b,c,y,x] = featbuf[inv[b,y,x]][c] or 0 (verified R8)
__global__ __launch_bounds__(256) void write_out(
    const int* __restrict__ inv, const float* __restrict__ featbuf,
    float* __restrict__ out)
{
    const unsigned TOT = 4u * C_IN * H_Y * W_X;
    for (unsigned i = blockIdx.x * 256 + threadIdx.x; i < TOT; i += 2048u * 256u) {
        const unsigned x = i % W_X;
        const unsigned t1 = i / W_X;
        const unsigned y = t1 % H_Y;
        const unsigned t2 = t1 / H_Y;
        const unsigned c = t2 & 127u;
        const unsigned b = t2 >> 7;
        const int m = inv[(b * H_Y + y) * W_X + x];
        out[i] = (m >= 0) ? featbuf[(unsigned)m * C_IN + c] : 0.0f;
    }
}

// ---- generic GEMV pass: out[m][c] = [gelu](in[m][:K].W[c][:K] + bias[c]) [+ res[m][c]]
// 2 queries / 512-thread block; 2 threads per output (R8 pattern).
template<int K, bool GELU, bool RES>
__global__ __launch_bounds__(512) void k_gemv(
    const float* __restrict__ in, const float* __restrict__ W,
    const float* __restrict__ bias, const float* __restrict__ res,
    float* __restrict__ outp, const int M)
{
    __shared__ float in_l[2][K];
    const int tid = threadIdx.x;
    const int mA = blockIdx.x * 2;
    const int mB = (mA + 1 < M) ? (mA + 1) : (M - 1);

    for (int i = tid; i < 2 * K; i += 512) {
        const int q = i / K, k = i % K;
        in_l[q][k] = in[(size_t)(q ? mB : mA) * K + k];
    }
    __syncthreads();

    const int q = tid >> 8, c = (tid >> 1) & 127, half = tid & 1;
    const float4* wr = (const float4*)(W + (size_t)c * K + half * (K / 2));
    const float4* ir = (const float4*)(&in_l[q][half * (K / 2)]);
    float acc = 0.f;
    #pragma unroll
    for (int k = 0; k < K / 8; ++k) acc += dot4(wr[k], ir[k]);
    acc += __shfl_xor(acc, 1);
    if (half == 0) {
        const int m = q ? mB : mA;
        float v = acc + bias[c];
        if (GELU) v = gelu_exact(v);
        if (RES)  v += res[(size_t)m * C_IN + c];
        outp[(size_t)m * C_IN + c] = v;
    }
}

// ---- LayerNorm pass: out[m] = LN(in[m])*g + be   (2 q / 512-thread block)
__global__ __launch_bounds__(512) void k_ln(
    const float* __restrict__ in, const float* __restrict__ g,
    const float* __restrict__ be, float* __restrict__ outp, const int M)
{
    __shared__ float in_l[2][C_IN];
    const int tid = threadIdx.x;
    const int mA = blockIdx.x * 2;
    const int mB = (mA + 1 < M) ? (mA + 1) : (M - 1);

    if (tid < 256) {
        const int q = tid >> 7, idx = tid & 127;
        in_l[q][idx] = in[(size_t)(q ? mB : mA) * C_IN + idx];
    }
    __syncthreads();

    const int q = tid >> 8, lane = tid & 63;
    const float v0 = in_l[q][lane], v1 = in_l[q][lane + 64];
    float s = v0 + v1;
    #pragma unroll
    for (int o = 32; o >= 1; o >>= 1) s += __shfl_xor(s, o);
    const float mean = s * (1.0f / 128.0f);
    const float d0 = v0 - mean, d1 = v1 - mean;
    float vv = d0 * d0 + d1 * d1;
    #pragma unroll
    for (int o = 32; o >= 1; o >>= 1) vv += __shfl_xor(vv, o);
    const float rs = rsqrtf(vv * (1.0f / 128.0f) + 1e-5f);
    if ((tid & 255) < 128) {
        const int idx = tid & 127;
        const float myv = (idx < 64) ? v0 : v1;
        outp[(size_t)(q ? mB : mA) * C_IN + idx] = (myv - mean) * rs * g[idx] + be[idx];
    }
}

// ---- attention kernel: key gather + posemb + LN_k + low-rank attention.
// 2 queries / 512-thread block. Reads qh (precomputed); writes av.
//   t[h] = qh_h @ wk_h ; logits[h,p] = (t[h].k[p] + qh_h.bk_h)*s
//   kbar[h] = sum_p attn[h,p] k[p] ; av[j] = kbar[h(j)].wv_row(j) + bv[j]
__global__ __launch_bounds__(512) void k_attn(
    const float* __restrict__ vf, const int* __restrict__ spi,
    const int* __restrict__ ni, const int* __restrict__ kidx,
    const float* __restrict__ qh_g,
    const float* __restrict__ w_pos, const float* __restrict__ b_pos,
    const float* __restrict__ g_k, const float* __restrict__ be_k,
    const float* __restrict__ w_in, const float* __restrict__ b_in,
    float* __restrict__ av_g, const int M)
{
    const int tid = threadIdx.x;
    const int m2 = blockIdx.x * 2;
    const int mA = m2;
    const int mB = (m2 + 1 < M) ? (m2 + 1) : (M - 1);

    __shared__ ushort kf16[64][C_IN + 8];   // 17.4 KB
    __shared__ float qhs[2 * C_IN];
    __shared__ float tk[2 * 4 * C_IN];      // t, then kbar
    __shared__ float attnw[2 * 4 * NKEY];
    __shared__ int   kmsk[64];

    const int nxA = ni[mA*4+3], nyA = ni[mA*4+2];
    const int nxB = ni[mB*4+3], nyB = ni[mB*4+2];

    // ---- P1: 64 key rows x 8 threads (verbatim R8)
    {
        const int kk = tid >> 3;
        const int qk = kk >> 5;
        const int g  = tid & 7;
        const int c0 = g * 16;
        const int mq = qk ? mB : mA;
        const int nxk = qk ? nxB : nxA, nyk = qk ? nyB : nyA;
        const float qxk = (nxk + 0.5f) * (150.4f / 180.0f) - 75.2f;
        const float qyk = (nyk + 0.5f) * (150.4f / 180.0f) - 75.2f;

        const int kv = kidx[mq * NKEY + (kk & 31)];
        if (g == 0) kmsk[kk] = (kv < 0) ? 1 : 0;
        const int safe = (kv < 0) ? 0 : kv;
        const int sz = spi[safe * 4 + 1];
        const int sy = spi[safe * 4 + 2];
        const int sx = spi[safe * 4 + 3];
        const float cx = (sx + 0.5f) * (150.4f / 1440.0f) - 75.2f - qxk;
        const float cy = (sy + 0.5f) * (150.4f / 1440.0f) - 75.2f - qyk;
        const float cz = (sz + 0.5f) * (6.0f / 40.0f)     - 2.0f  - 1.0f;

        float v[16];
        const float4* src = (const float4*)(vf + (size_t)safe * C_IN + c0);
        #pragma unroll
        for (int j = 0; j < 4; ++j) {
            float4 t = src[j];
            v[j*4+0] = t.x; v[j*4+1] = t.y; v[j*4+2] = t.z; v[j*4+3] = t.w;
        }
        #pragma unroll
        for (int j = 0; j < 16; ++j) {
            const int c = c0 + j;
            float e = cx * w_pos[c*3+0] + cy * w_pos[c*3+1] + cz * w_pos[c*3+2] + b_pos[c];
            v[j] += gelu_exact(e);
        }
        float s = 0.f;
        #pragma unroll
        for (int j = 0; j < 16; ++j) s += v[j];
        s += __shfl_xor(s, 1); s += __shfl_xor(s, 2); s += __shfl_xor(s, 4);
        const float mean = s * (1.0f / 128.0f);
        float vv = 0.f;
        #pragma unroll
        for (int j = 0; j < 16; ++j) { float d = v[j] - mean; vv += d * d; }
        vv += __shfl_xor(vv, 1); vv += __shfl_xor(vv, 2); vv += __shfl_xor(vv, 4);
        const float rs = rsqrtf(vv * (1.0f / 128.0f) + 1e-5f);
        ushort o[16];
        #pragma unroll
        for (int j = 0; j < 16; ++j) {
            const int c = c0 + j;
            o[j] = f2bf((v[j] - mean) * rs * g_k[c] + be_k[c]);
        }
        short8* drow = (short8*)(&kf16[kk][c0]);
        drow[0] = *(short8*)&o[0];
        drow[1] = *(short8*)&o[8];
    }

    // stage qh
    if (tid < 256) {
        const int q = tid >> 7, idx = tid & 127;
        qhs[q * 128 + idx] = qh_g[(size_t)(q ? mB : mA) * C_IN + idx];
    }
    __syncthreads();

    // ---- t[h] = qh_h @ wk_h (verbatim R8)
    {
        const int q = tid >> 8, r = tid & 255;
        const int c = r & 127, h2 = r >> 7;
        #pragma unroll
        for (int hi = 0; hi < 2; ++hi) {
            const int hh = h2 + 2 * hi;
            float acc = 0.f;
            #pragma unroll
            for (int d = 0; d < D_H; ++d)
                acc += qhs[q*128 + hh*D_H + d] * w_in[(size_t)(C_IN + hh*D_H + d) * C_IN + c];
            tk[(q*4 + hh)*128 + c] = acc;
        }
    }
    __syncthreads();

    // ---- logits + masked softmax (verbatim R8)
    if (tid < 256) {
        const int q = tid >> 7, h = (tid >> 5) & 3, p = tid & 31;
        float tbv = qhs[q*128 + h*D_H + p] * b_in[C_IN + h*D_H + p];
        #pragma unroll
        for (int o = 16; o >= 1; o >>= 1) tbv += __shfl_xor(tbv, o);
        const float* tr = &tk[(q*4 + h)*128];
        const ushort* kr = kf16[q*NKEY + p];
        float d = 0.f;
        #pragma unroll
        for (int c2 = 0; c2 < 64; ++c2) {
            const uint u = *(const uint*)&kr[c2*2];
            d += tr[c2*2]   * bf2f((ushort)(u & 0xffff));
            d += tr[c2*2+1] * bf2f((ushort)(u >> 16));
        }
        const int msk = kmsk[q*NKEY + p];
        float logit = msk ? -3.0e38f : (d + tbv) * 0.17677669529663687f;
        float mx = logit;
        #pragma unroll
        for (int o = 16; o >= 1; o >>= 1) mx = fmaxf(mx, __shfl_xor(mx, o));
        const float e = msk ? 0.0f : expf(logit - mx);
        float ssum = e;
        #pragma unroll
        for (int o = 16; o >= 1; o >>= 1) ssum += __shfl_xor(ssum, o);
        attnw[(q*4 + h)*32 + p] = e / ssum;
    }
    __syncthreads();

    // ---- kbar[h] = sum_p attn[h,p] k[p] (verbatim R8, overwrites tk)
    {
        const int q = tid >> 8, r = tid & 255;
        const int c = r & 127, h2 = r >> 7;
        #pragma unroll
        for (int hi = 0; hi < 2; ++hi) {
            const int hh = h2 + 2 * hi;
            float acc = 0.f;
            #pragma unroll
            for (int p = 0; p < NKEY; ++p)
                acc += attnw[(q*4 + hh)*32 + p] * bf2f(kf16[q*NKEY + p][c]);
            tk[(q*4 + hh)*128 + c] = acc;
        }
    }
    __syncthreads();

    // ---- av[j] = kbar[h(j)].wv_row(j) + bv[j] -> global (verbatim R8 + store)
    {
        const int q = tid >> 8, j = (tid >> 1) & 127, half = tid & 1;
        const int h = j >> 5;
        const float4* wr = (const float4*)(w_in + (size_t)(2*C_IN + j) * C_IN + half * 64);
        const float4* kb = (const float4*)(&tk[(q*4 + h)*128 + half * 64]);
        float acc = 0.f;
        #pragma unroll
        for (int k = 0; k < 16; ++k) acc += dot4(wr[k], kb[k]);
        acc += __shfl_xor(acc, 1);
        if (half == 0 && (m2 + q) < M) {
            av_g[(size_t)(q ? mB : mA) * C_IN + j] = acc + b_in[2*C_IN + j];
        }
    }
}

extern "C" void kernel_launch(void* const* d_in, const int* in_sizes, int n_in,
                              void* d_out, int out_size, void* d_ws, size_t ws_size,
                              hipStream_t stream) {
    const float* vf    = (const float*)d_in[0];
    const int*   spi   = (const int*)  d_in[1];
    const int*   ni    = (const int*)  d_in[2];
    const int*   kidx  = (const int*)  d_in[3];
    const float* bev   = (const float*)d_in[4];
    const float* w_pos = (const float*)d_in[5];
    const float* b_pos = (const float*)d_in[6];
    const float* w_bev = (const float*)d_in[7];
    const float* b_bev = (const float*)d_in[8];
    const float* g_q   = (const float*)d_in[9];
    const float* be_q  = (const float*)d_in[10];
    const float* g_k   = (const float*)d_in[11];
    const float* be_k  = (const float*)d_in[12];
    const float* g_f   = (const float*)d_in[13];
    const float* be_f  = (const float*)d_in[14];
    const float* w_in  = (const float*)d_in[15];
    const float* b_in  = (const float*)d_in[16];
    const float* w_out = (const float*)d_in[17];
    const float* b_out = (const float*)d_in[18];
    const float* w_fc1 = (const float*)d_in[19];
    const float* b_fc1 = (const float*)d_in[20];
    const float* w_fc2 = (const float*)d_in[21];
    const float* b_fc2 = (const float*)d_in[22];
    float* out = (float*)d_out;

    const int M = in_sizes[3] / NKEY;
    const int npairs = (M + 1) / 2;

    // ---- workspace layout (~50 MB, aliased):
    //  inv  @0        (4 MB reserved)
    //  bevq @4MB      (30.72 MB)  -- dead after k_sc, then hosts A and B:
    //    A  @4MB      (15.36 MB)  : qln -> av -> h1
    //    B  @4MB+15.36(15.36 MB)  : qh -> yln -> featbuf
    //  scxf @36MB     (15.36 MB)  : sc, then xf written in-place by k_wout
    char* ws = (char*)d_ws;
    const size_t MB = 1u << 20;
    int*   inv  = (int*)ws;
    float* bevq = (float*)(ws + 4 * MB);
    float* A    = (float*)(ws + 4 * MB);
    float* B    = (float*)(ws + 4 * MB + (size_t)M * C_IN * sizeof(float));
    float* scxf = (float*)(ws + 36 * MB);

    hipMemsetAsync(inv, 0xFF, (size_t)4 * H_Y * W_X * sizeof(int), stream);
    build_inv<<<(M + 255) / 256, 256, 0, stream>>>(ni, inv, M);
    compact_bev<<<4 * H_Y * 12, 256, 0, stream>>>(bev, inv, bevq);

    // sc = gelu(bevq @ w_bev^T + b_bev)
    k_gemv<C_BEV, true, false><<<npairs, 512, 0, stream>>>(bevq, w_bev, b_bev, nullptr, scxf, M);
    // qln = LN(sc)
    k_ln<<<npairs, 512, 0, stream>>>(scxf, g_q, be_q, A, M);
    // qh = qln @ wq^T + bq
    k_gemv<C_IN, false, false><<<npairs, 512, 0, stream>>>(A, w_in, b_in, nullptr, B, M);
    // attention (gathers keys internally) -> av
    k_attn<<<npairs, 512, 0, stream>>>(vf, spi, ni, kidx, B, w_pos, b_pos,
                                       g_k, be_k, w_in, b_in, A, M);
    // xf = av @ w_out^T + b_out + sc   (in-place over sc)
    k_gemv<C_IN, false, true><<<npairs, 512, 0, stream>>>(A, w_out, b_out, scxf, scxf, M);
    // yln = LN(xf)
    k_ln<<<npairs, 512, 0, stream>>>(scxf, g_f, be_f, B, M);
    // h1 = gelu(yln @ w_fc1^T + b_fc1)
    k_gemv<C_IN, true, false><<<npairs, 512, 0, stream>>>(B, w_fc1, b_fc1, nullptr, A, M);
    // featbuf = h1 @ w_fc2^T + b_fc2 + xf
    k_gemv<C_IN, false, true><<<npairs, 512, 0, stream>>>(A, w_fc2, b_fc2, scxf, B, M);

    write_out<<<2048, 256, 0, stream>>>(inv, B, out);
}

// Round 16
// 2075.652 us; speedup vs baseline: 2.7491x; 1.0044x over previous
//
#include <hip/hip_runtime.h>
#include <hip/hip_bf16.h>
#include <cmath>

#define C_IN 128
#define NKEY 32
#define N_H 4
#define D_H 32
#define C_BEV 256
#define H_Y 180
#define W_X 180

typedef __attribute__((ext_vector_type(8))) short short8;

__device__ __forceinline__ float gelu_exact(float x) {
    return 0.5f * x * (1.0f + erff(x * 0.7071067811865475f));
}
__device__ __forceinline__ float dot4(float4 a, float4 b) {
    return a.x * b.x + a.y * b.y + a.z * b.z + a.w * b.w;
}
__device__ __forceinline__ float bf2f(ushort u) {
    union { unsigned int i; float f; } c; c.i = ((unsigned int)u) << 16; return c.f;
}
__device__ __forceinline__ ushort f2bf(float x) {
    __hip_bfloat16 h = __float2bfloat16(x);
    return *reinterpret_cast<ushort*>(&h);
}

// ---- inv[cell] = m  (inv pre-memset to -1)
__global__ void build_inv(const int* __restrict__ ni, int* __restrict__ inv, int M) {
    const int m = blockIdx.x * 256 + threadIdx.x;
    if (m < M) {
        const int b = ni[m*4+0], y = ni[m*4+2], x = ni[m*4+3];
        inv[(b * H_Y + y) * W_X + x] = m;
    }
}

// ---- compact bev -> pack[m][0:256] contiguous (verified R8/R13)
__global__ __launch_bounds__(256) void compact_bev(
    const float* __restrict__ bev, const int* __restrict__ inv,
    float* __restrict__ pack)
{
    const int bid = blockIdx.x;
    const int xr = bid % 12;
    const int y  = (bid / 12) % H_Y;
    const int b  = bid / (12 * H_Y);
    const int x0 = xr * 16;
    const int width = (x0 + 16 <= W_X) ? 16 : (W_X - x0);
    const int tid = threadIdx.x;

    __shared__ float tile[16][257];

    const int xq = (tid & 3) * 4;
    #pragma unroll
    for (int p = 0; p < 4; ++p) {
        const int c = p * 64 + (tid >> 2);
        if (xq < width) {
            const float4 v = *(const float4*)(bev +
                (((size_t)b * C_BEV + c) * H_Y + y) * W_X + x0 + xq);
            tile[xq+0][c] = v.x; tile[xq+1][c] = v.y;
            tile[xq+2][c] = v.z; tile[xq+3][c] = v.w;
        }
    }
    __syncthreads();
    for (int xi = 0; xi < width; ++xi) {
        const int m = inv[(b * H_Y + y) * W_X + x0 + xi];
        if (m >= 0) pack[(size_t)m * C_BEV + tid] = tile[xi][tid];
    }
}

// ---- out[b,c,y,x] = featbuf[inv[b,y,x]][c] or 0 (verified R8/R13)
__global__ __launch_bounds__(256) void write_out(
    const int* __restrict__ inv, const float* __restrict__ featbuf,
    float* __restrict__ out)
{
    const unsigned TOT = 4u * C_IN * H_Y * W_X;
    for (unsigned i = blockIdx.x * 256 + threadIdx.x; i < TOT; i += 2048u * 256u) {
        const unsigned x = i % W_X;
        const unsigned t1 = i / W_X;
        const unsigned y = t1 % H_Y;
        const unsigned t2 = t1 / H_Y;
        const unsigned c = t2 & 127u;
        const unsigned b = t2 >> 7;
        const int m = inv[(b * H_Y + y) * W_X + x];
        out[i] = (m >= 0) ? featbuf[(unsigned)m * C_IN + c] : 0.0f;
    }
}

// ---- fused pre-attention: sc = gelu(bevq @ w_bev^T + b_bev); qln = LN(sc);
//      qh = qln @ wq^T + bq.  2 queries / 512-thread block.
//      pack row m: [0:256] bevq on input; qh written in-place to [0:128].
__global__ __launch_bounds__(512) void k_pre(
    float* __restrict__ pack, const float* __restrict__ w_bev,
    const float* __restrict__ b_bev, const float* __restrict__ g_q,
    const float* __restrict__ be_q, const float* __restrict__ w_in,
    const float* __restrict__ b_in, float* __restrict__ sc_g, const int M)
{
    __shared__ float bevl[2][C_BEV];
    __shared__ float scl[2][C_IN];
    __shared__ float qlnl[2][C_IN];
    const int tid = threadIdx.x;
    const int mA = blockIdx.x * 2;
    const int mB = (mA + 1 < M) ? (mA + 1) : (M - 1);

    // stage bevq (one element per thread: 512 = 2x256)
    {
        const int q = tid >> 8, k = tid & 255;
        bevl[q][k] = pack[(size_t)(q ? mB : mA) * C_BEV + k];
    }
    __syncthreads();

    // sc = gelu(bev @ w_bev^T + b_bev)
    {
        const int q = tid >> 8, c = (tid >> 1) & 127, half = tid & 1;
        const float4* wr = (const float4*)(w_bev + (size_t)c * C_BEV + half * 128);
        const float4* br = (const float4*)(&bevl[q][half * 128]);
        float acc = 0.f;
        #pragma unroll
        for (int k = 0; k < 32; ++k) acc += dot4(wr[k], br[k]);
        acc += __shfl_xor(acc, 1);
        if (half == 0) {
            const float v = gelu_exact(acc + b_bev[c]);
            scl[q][c] = v;
            sc_g[(size_t)(q ? mB : mA) * C_IN + c] = v;
        }
    }
    __syncthreads();

    // qln = LN(sc)
    {
        const int q = tid >> 8, lane = tid & 63;
        const float v0 = scl[q][lane], v1 = scl[q][lane + 64];
        float s = v0 + v1;
        #pragma unroll
        for (int o = 32; o >= 1; o >>= 1) s += __shfl_xor(s, o);
        const float mean = s * (1.0f / 128.0f);
        const float d0 = v0 - mean, d1 = v1 - mean;
        float vv = d0 * d0 + d1 * d1;
        #pragma unroll
        for (int o = 32; o >= 1; o >>= 1) vv += __shfl_xor(vv, o);
        const float rs = rsqrtf(vv * (1.0f / 128.0f) + 1e-5f);
        if ((tid & 255) < 128) {
            const int idx = tid & 127;
            const float myv = (idx < 64) ? v0 : v1;
            qlnl[q][idx] = (myv - mean) * rs * g_q[idx] + be_q[idx];
        }
    }
    __syncthreads();

    // qh = qln @ wq^T + bq -> pack[m][0:128] (in-place; own rows only)
    {
        const int q = tid >> 8, c = (tid >> 1) & 127, half = tid & 1;
        const float4* wr = (const float4*)(w_in + (size_t)c * C_IN + half * 64);
        const float4* qr = (const float4*)(&qlnl[q][half * 64]);
        float acc = 0.f;
        #pragma unroll
        for (int k = 0; k < 16; ++k) acc += dot4(wr[k], qr[k]);
        acc += __shfl_xor(acc, 1);
        if (half == 0)
            pack[(size_t)(q ? mB : mA) * C_BEV + c] = acc + b_in[c];
    }
}

// ---- attention kernel (R13 body; qh from pack[m][0:128], av to pack[m][128:256])
__global__ __launch_bounds__(512) void k_attn(
    const float* __restrict__ vf, const int* __restrict__ spi,
    const int* __restrict__ ni, const int* __restrict__ kidx,
    float* __restrict__ pack,
    const float* __restrict__ w_pos, const float* __restrict__ b_pos,
    const float* __restrict__ g_k, const float* __restrict__ be_k,
    const float* __restrict__ w_in, const float* __restrict__ b_in,
    const int M)
{
    const int tid = threadIdx.x;
    const int m2 = blockIdx.x * 2;
    const int mA = m2;
    const int mB = (m2 + 1 < M) ? (m2 + 1) : (M - 1);

    __shared__ ushort kf16[64][C_IN + 8];
    __shared__ float qhs[2 * C_IN];
    __shared__ float tk[2 * 4 * C_IN];
    __shared__ float attnw[2 * 4 * NKEY];
    __shared__ int   kmsk[64];

    const int nxA = ni[mA*4+3], nyA = ni[mA*4+2];
    const int nxB = ni[mB*4+3], nyB = ni[mB*4+2];

    // ---- P1: 64 key rows x 8 threads (verbatim R8/R13)
    {
        const int kk = tid >> 3;
        const int qk = kk >> 5;
        const int g  = tid & 7;
        const int c0 = g * 16;
        const int mq = qk ? mB : mA;
        const int nxk = qk ? nxB : nxA, nyk = qk ? nyB : nyA;
        const float qxk = (nxk + 0.5f) * (150.4f / 180.0f) - 75.2f;
        const float qyk = (nyk + 0.5f) * (150.4f / 180.0f) - 75.2f;

        const int kv = kidx[mq * NKEY + (kk & 31)];
        if (g == 0) kmsk[kk] = (kv < 0) ? 1 : 0;
        const int safe = (kv < 0) ? 0 : kv;
        const int sz = spi[safe * 4 + 1];
        const int sy = spi[safe * 4 + 2];
        const int sx = spi[safe * 4 + 3];
        const float cx = (sx + 0.5f) * (150.4f / 1440.0f) - 75.2f - qxk;
        const float cy = (sy + 0.5f) * (150.4f / 1440.0f) - 75.2f - qyk;
        const float cz = (sz + 0.5f) * (6.0f / 40.0f)     - 2.0f  - 1.0f;

        float v[16];
        const float4* src = (const float4*)(vf + (size_t)safe * C_IN + c0);
        #pragma unroll
        for (int j = 0; j < 4; ++j) {
            float4 t = src[j];
            v[j*4+0] = t.x; v[j*4+1] = t.y; v[j*4+2] = t.z; v[j*4+3] = t.w;
        }
        #pragma unroll
        for (int j = 0; j < 16; ++j) {
            const int c = c0 + j;
            float e = cx * w_pos[c*3+0] + cy * w_pos[c*3+1] + cz * w_pos[c*3+2] + b_pos[c];
            v[j] += gelu_exact(e);
        }
        float s = 0.f;
        #pragma unroll
        for (int j = 0; j < 16; ++j) s += v[j];
        s += __shfl_xor(s, 1); s += __shfl_xor(s, 2); s += __shfl_xor(s, 4);
        const float mean = s * (1.0f / 128.0f);
        float vv = 0.f;
        #pragma unroll
        for (int j = 0; j < 16; ++j) { float d = v[j] - mean; vv += d * d; }
        vv += __shfl_xor(vv, 1); vv += __shfl_xor(vv, 2); vv += __shfl_xor(vv, 4);
        const float rs = rsqrtf(vv * (1.0f / 128.0f) + 1e-5f);
        ushort o[16];
        #pragma unroll
        for (int j = 0; j < 16; ++j) {
            const int c = c0 + j;
            o[j] = f2bf((v[j] - mean) * rs * g_k[c] + be_k[c]);
        }
        short8* drow = (short8*)(&kf16[kk][c0]);
        drow[0] = *(short8*)&o[0];
        drow[1] = *(short8*)&o[8];
    }

    // stage qh from pack[m][0:128]
    if (tid < 256) {
        const int q = tid >> 7, idx = tid & 127;
        qhs[q * 128 + idx] = pack[(size_t)(q ? mB : mA) * C_BEV + idx];
    }
    __syncthreads();

    // ---- t[h] = qh_h @ wk_h
    {
        const int q = tid >> 8, r = tid & 255;
        const int c = r & 127, h2 = r >> 7;
        #pragma unroll
        for (int hi = 0; hi < 2; ++hi) {
            const int hh = h2 + 2 * hi;
            float acc = 0.f;
            #pragma unroll
            for (int d = 0; d < D_H; ++d)
                acc += qhs[q*128 + hh*D_H + d] * w_in[(size_t)(C_IN + hh*D_H + d) * C_IN + c];
            tk[(q*4 + hh)*128 + c] = acc;
        }
    }
    __syncthreads();

    // ---- logits + masked softmax
    if (tid < 256) {
        const int q = tid >> 7, h = (tid >> 5) & 3, p = tid & 31;
        float tbv = qhs[q*128 + h*D_H + p] * b_in[C_IN + h*D_H + p];
        #pragma unroll
        for (int o = 16; o >= 1; o >>= 1) tbv += __shfl_xor(tbv, o);
        const float* tr = &tk[(q*4 + h)*128];
        const ushort* kr = kf16[q*NKEY + p];
        float d = 0.f;
        #pragma unroll
        for (int c2 = 0; c2 < 64; ++c2) {
            const uint u = *(const uint*)&kr[c2*2];
            d += tr[c2*2]   * bf2f((ushort)(u & 0xffff));
            d += tr[c2*2+1] * bf2f((ushort)(u >> 16));
        }
        const int msk = kmsk[q*NKEY + p];
        float logit = msk ? -3.0e38f : (d + tbv) * 0.17677669529663687f;
        float mx = logit;
        #pragma unroll
        for (int o = 16; o >= 1; o >>= 1) mx = fmaxf(mx, __shfl_xor(mx, o));
        const float e = msk ? 0.0f : expf(logit - mx);
        float ssum = e;
        #pragma unroll
        for (int o = 16; o >= 1; o >>= 1) ssum += __shfl_xor(ssum, o);
        attnw[(q*4 + h)*32 + p] = e / ssum;
    }
    __syncthreads();

    // ---- kbar[h] = sum_p attn[h,p] k[p] (overwrites tk)
    {
        const int q = tid >> 8, r = tid & 255;
        const int c = r & 127, h2 = r >> 7;
        #pragma unroll
        for (int hi = 0; hi < 2; ++hi) {
            const int hh = h2 + 2 * hi;
            float acc = 0.f;
            #pragma unroll
            for (int p = 0; p < NKEY; ++p)
                acc += attnw[(q*4 + hh)*32 + p] * bf2f(kf16[q*NKEY + p][c]);
            tk[(q*4 + hh)*128 + c] = acc;
        }
    }
    __syncthreads();

    // ---- av[j] = kbar[h(j)].wv_row(j) + bv[j] -> pack[m][128:256]
    {
        const int q = tid >> 8, j = (tid >> 1) & 127, half = tid & 1;
        const int h = j >> 5;
        const float4* wr = (const float4*)(w_in + (size_t)(2*C_IN + j) * C_IN + half * 64);
        const float4* kb = (const float4*)(&tk[(q*4 + h)*128 + half * 64]);
        float acc = 0.f;
        #pragma unroll
        for (int k = 0; k < 16; ++k) acc += dot4(wr[k], kb[k]);
        acc += __shfl_xor(acc, 1);
        if (half == 0 && (m2 + q) < M) {
            pack[(size_t)(q ? mB : mA) * C_BEV + C_IN + j] = acc + b_in[2*C_IN + j];
        }
    }
}

// ---- fused post-attention: xf = av @ w_out^T + b_out + sc; yln = LN(xf);
//      h1 = gelu(yln @ w_fc1^T + b_fc1); feat = h1 @ w_fc2^T + b_fc2 + xf.
//      featbuf written IN-PLACE over sc (scfeat). 2 queries / 512-thread block.
__global__ __launch_bounds__(512) void k_post(
    const float* __restrict__ pack,   // av at [m][128:256]
    const float* __restrict__ w_out, const float* __restrict__ b_out,
    const float* __restrict__ g_f, const float* __restrict__ be_f,
    const float* __restrict__ w_fc1, const float* __restrict__ b_fc1,
    const float* __restrict__ w_fc2, const float* __restrict__ b_fc2,
    float* __restrict__ scfeat, const int M)
{
    __shared__ float avl[2][C_IN];
    __shared__ float xfl[2][C_IN];
    __shared__ float ylnl[2][C_IN];
    __shared__ float h1l[2][C_IN];
    const int tid = threadIdx.x;
    const int mA = blockIdx.x * 2;
    const int mB = (mA + 1 < M) ? (mA + 1) : (M - 1);

    if (tid < 256) {
        const int q = tid >> 7, i = tid & 127;
        avl[q][i] = pack[(size_t)(q ? mB : mA) * C_BEV + C_IN + i];
    }
    __syncthreads();

    // xf = av @ w_out^T + b_out + sc
    {
        const int q = tid >> 8, c = (tid >> 1) & 127, half = tid & 1;
        const float4* wr = (const float4*)(w_out + (size_t)c * C_IN + half * 64);
        const float4* ar = (const float4*)(&avl[q][half * 64]);
        float acc = 0.f;
        #pragma unroll
        for (int k = 0; k < 16; ++k) acc += dot4(wr[k], ar[k]);
        acc += __shfl_xor(acc, 1);
        if (half == 0)
            xfl[q][c] = acc + b_out[c] + scfeat[(size_t)(q ? mB : mA) * C_IN + c];
    }
    __syncthreads();

    // yln = LN(xf)
    {
        const int q = tid >> 8, lane = tid & 63;
        const float v0 = xfl[q][lane], v1 = xfl[q][lane + 64];
        float s = v0 + v1;
        #pragma unroll
        for (int o = 32; o >= 1; o >>= 1) s += __shfl_xor(s, o);
        const float mean = s * (1.0f / 128.0f);
        const float d0 = v0 - mean, d1 = v1 - mean;
        float vv = d0 * d0 + d1 * d1;
        #pragma unroll
        for (int o = 32; o >= 1; o >>= 1) vv += __shfl_xor(vv, o);
        const float rs = rsqrtf(vv * (1.0f / 128.0f) + 1e-5f);
        if ((tid & 255) < 128) {
            const int idx = tid & 127;
            const float myv = (idx < 64) ? v0 : v1;
            ylnl[q][idx] = (myv - mean) * rs * g_f[idx] + be_f[idx];
        }
    }
    __syncthreads();

    // h1 = gelu(yln @ w_fc1^T + b_fc1)
    {
        const int q = tid >> 8, c = (tid >> 1) & 127, half = tid & 1;
        const float4* wr = (const float4*)(w_fc1 + (size_t)c * C_IN + half * 64);
        const float4* yr = (const float4*)(&ylnl[q][half * 64]);
        float acc = 0.f;
        #pragma unroll
        for (int k = 0; k < 16; ++k) acc += dot4(wr[k], yr[k]);
        acc += __shfl_xor(acc, 1);
        if (half == 0) h1l[q][c] = gelu_exact(acc + b_fc1[c]);
    }
    __syncthreads();

    // feat = h1 @ w_fc2^T + b_fc2 + xf -> scfeat in-place
    {
        const int q = tid >> 8, c = (tid >> 1) & 127, half = tid & 1;
        const float4* wr = (const float4*)(w_fc2 + (size_t)c * C_IN + half * 64);
        const float4* hr = (const float4*)(&h1l[q][half * 64]);
        float acc = 0.f;
        #pragma unroll
        for (int k = 0; k < 16; ++k) acc += dot4(wr[k], hr[k]);
        acc += __shfl_xor(acc, 1);
        if (half == 0 && (mA + q) < M) {
            scfeat[(size_t)(q ? mB : mA) * C_IN + c] = acc + b_fc2[c] + xfl[q][c];
        }
    }
}

extern "C" void kernel_launch(void* const* d_in, const int* in_sizes, int n_in,
                              void* d_out, int out_size, void* d_ws, size_t ws_size,
                              hipStream_t stream) {
    const float* vf    = (const float*)d_in[0];
    const int*   spi   = (const int*)  d_in[1];
    const int*   ni    = (const int*)  d_in[2];
    const int*   kidx  = (const int*)  d_in[3];
    const float* bev   = (const float*)d_in[4];
    const float* w_pos = (const float*)d_in[5];
    const float* b_pos = (const float*)d_in[6];
    const float* w_bev = (const float*)d_in[7];
    const float* b_bev = (const float*)d_in[8];
    const float* g_q   = (const float*)d_in[9];
    const float* be_q  = (const float*)d_in[10];
    const float* g_k   = (const float*)d_in[11];
    const float* be_k  = (const float*)d_in[12];
    const float* g_f   = (const float*)d_in[13];
    const float* be_f  = (const float*)d_in[14];
    const float* w_in  = (const float*)d_in[15];
    const float* b_in  = (const float*)d_in[16];
    const float* w_out = (const float*)d_in[17];
    const float* b_out = (const float*)d_in[18];
    const float* w_fc1 = (const float*)d_in[19];
    const float* b_fc1 = (const float*)d_in[20];
    const float* w_fc2 = (const float*)d_in[21];
    const float* b_fc2 = (const float*)d_in[22];
    float* out = (float*)d_out;

    const int M = in_sizes[3] / NKEY;
    const int npairs = (M + 1) / 2;

    // ---- workspace (max end ~46.7 MiB; R13 used 50.7 MiB OK):
    //  inv    @0      (1.98 MiB)
    //  pack   @2MiB   [M][256] f32 (29.3 MiB): bevq -> row[0:128]=qh, row[128:256]=av
    //  scfeat @32MiB  [M][128] f32 (14.65 MiB): sc, then featbuf in-place
    char* ws = (char*)d_ws;
    const size_t MiB = 1u << 20;
    int*   inv    = (int*)ws;
    float* pack   = (float*)(ws + 2 * MiB);
    float* scfeat = (float*)(ws + 32 * MiB);

    hipMemsetAsync(inv, 0xFF, (size_t)4 * H_Y * W_X * sizeof(int), stream);
    build_inv<<<(M + 255) / 256, 256, 0, stream>>>(ni, inv, M);
    compact_bev<<<4 * H_Y * 12, 256, 0, stream>>>(bev, inv, pack);

    k_pre<<<npairs, 512, 0, stream>>>(pack, w_bev, b_bev, g_q, be_q, w_in, b_in, scfeat, M);
    k_attn<<<npairs, 512, 0, stream>>>(vf, spi, ni, kidx, pack, w_pos, b_pos,
                                       g_k, be_k, w_in, b_in, M);
    k_post<<<npairs, 512, 0, stream>>>(pack, w_out, b_out, g_f, be_f,
                                       w_fc1, b_fc1, w_fc2, b_fc2, scfeat, M);

    write_out<<<2048, 256, 0, stream>>>(inv, scfeat, out);
}

// Round 17
// 1538.104 us; speedup vs baseline: 3.7099x; 1.3495x over previous
//
#include <hip/hip_runtime.h>
#include <hip/hip_bf16.h>
#include <cmath>

#define C_IN 128
#define NKEY 32
#define N_H 4
#define D_H 32
#define C_BEV 256
#define H_Y 180
#define W_X 180

typedef __attribute__((ext_vector_type(8))) short short8;

__device__ __forceinline__ float gelu_exact(float x) {
    return 0.5f * x * (1.0f + erff(x * 0.7071067811865475f));
}
__device__ __forceinline__ float dot4(float4 a, float4 b) {
    return a.x * b.x + a.y * b.y + a.z * b.z + a.w * b.w;
}
__device__ __forceinline__ float bf2f(ushort u) {
    union { unsigned int i; float f; } c; c.i = ((unsigned int)u) << 16; return c.f;
}
__device__ __forceinline__ ushort f2bf(float x) {
    __hip_bfloat16 h = __float2bfloat16(x);
    return *reinterpret_cast<ushort*>(&h);
}

// ---- inv[cell] = m  (inv pre-memset to -1)
__global__ void build_inv(const int* __restrict__ ni, int* __restrict__ inv, int M) {
    const int m = blockIdx.x * 256 + threadIdx.x;
    if (m < M) {
        const int b = ni[m*4+0], y = ni[m*4+2], x = ni[m*4+3];
        inv[(b * H_Y + y) * W_X + x] = m;
    }
}

// ---- compact bev -> pack[m][0:256] contiguous (verified R8/R13)
__global__ __launch_bounds__(256) void compact_bev(
    const float* __restrict__ bev, const int* __restrict__ inv,
    float* __restrict__ pack)
{
    const int bid = blockIdx.x;
    const int xr = bid % 12;
    const int y  = (bid / 12) % H_Y;
    const int b  = bid / (12 * H_Y);
    const int x0 = xr * 16;
    const int width = (x0 + 16 <= W_X) ? 16 : (W_X - x0);
    const int tid = threadIdx.x;

    __shared__ float tile[16][257];

    const int xq = (tid & 3) * 4;
    #pragma unroll
    for (int p = 0; p < 4; ++p) {
        const int c = p * 64 + (tid >> 2);
        if (xq < width) {
            const float4 v = *(const float4*)(bev +
                (((size_t)b * C_BEV + c) * H_Y + y) * W_X + x0 + xq);
            tile[xq+0][c] = v.x; tile[xq+1][c] = v.y;
            tile[xq+2][c] = v.z; tile[xq+3][c] = v.w;
        }
    }
    __syncthreads();
    for (int xi = 0; xi < width; ++xi) {
        const int m = inv[(b * H_Y + y) * W_X + x0 + xi];
        if (m >= 0) pack[(size_t)m * C_BEV + tid] = tile[xi][tid];
    }
}

// ---- out[b,c,y,x] = featbuf[inv[b,y,x]][c] or 0 (verified R8/R13)
__global__ __launch_bounds__(256) void write_out(
    const int* __restrict__ inv, const float* __restrict__ featbuf,
    float* __restrict__ out)
{
    const unsigned TOT = 4u * C_IN * H_Y * W_X;
    for (unsigned i = blockIdx.x * 256 + threadIdx.x; i < TOT; i += 2048u * 256u) {
        const unsigned x = i % W_X;
        const unsigned t1 = i / W_X;
        const unsigned y = t1 % H_Y;
        const unsigned t2 = t1 / H_Y;
        const unsigned c = t2 & 127u;
        const unsigned b = t2 >> 7;
        const int m = inv[(b * H_Y + y) * W_X + x];
        out[i] = (m >= 0) ? featbuf[(unsigned)m * C_IN + c] : 0.0f;
    }
}

// ---- fused pre-attention (COALESCED wave-GEMVs):
//   sc = gelu(bevq @ w_bev^T + b_bev); qln = LN(sc); qh = qln @ wq^T + bq.
//   2 queries / 512-thread block. qh -> pack[m][0:128] in-place.
__global__ __launch_bounds__(512) void k_pre(
    float* __restrict__ pack, const float* __restrict__ w_bev,
    const float* __restrict__ b_bev, const float* __restrict__ g_q,
    const float* __restrict__ be_q, const float* __restrict__ w_in,
    const float* __restrict__ b_in, float* __restrict__ sc_g, const int M)
{
    __shared__ float bevl[2][C_BEV];
    __shared__ float scl[2][C_IN];
    __shared__ float qlnl[2][C_IN];
    const int tid = threadIdx.x;
    const int mA = blockIdx.x * 2;
    const int mB = (mA + 1 < M) ? (mA + 1) : (M - 1);
    const int wave = tid >> 6, lane = tid & 63;

    // stage bevq (coalesced: 512 threads, 1 elem each)
    {
        const int q = tid >> 8, k = tid & 255;
        bevl[q][k] = pack[(size_t)(q ? mB : mA) * C_BEV + k];
    }
    __syncthreads();

    // sc: wave-per-row GEMV, K=256. Lane l reads w_bev[c][4l..4l+3] -> 1KB/wave coalesced.
    #pragma unroll 4
    for (int t = wave; t < 256; t += 8) {
        const int q = t >> 7, c = t & 127;
        const float4 w4 = ((const float4*)(w_bev + (size_t)c * C_BEV))[lane];
        const float4 b4 = ((const float4*)&bevl[q][0])[lane];
        float a = dot4(w4, b4);
        a += __shfl_xor(a, 1);  a += __shfl_xor(a, 2);  a += __shfl_xor(a, 4);
        a += __shfl_xor(a, 8);  a += __shfl_xor(a, 16); a += __shfl_xor(a, 32);
        const float v = gelu_exact(a + b_bev[c]);
        if (lane == 0) {
            scl[q][c] = v;
            sc_g[(size_t)(q ? mB : mA) * C_IN + c] = v;
        }
    }
    __syncthreads();

    // qln = LN(sc)  (unchanged)
    {
        const int q = tid >> 8, l2 = tid & 63;
        const float v0 = scl[q][l2], v1 = scl[q][l2 + 64];
        float s = v0 + v1;
        #pragma unroll
        for (int o = 32; o >= 1; o >>= 1) s += __shfl_xor(s, o);
        const float mean = s * (1.0f / 128.0f);
        const float d0 = v0 - mean, d1 = v1 - mean;
        float vv = d0 * d0 + d1 * d1;
        #pragma unroll
        for (int o = 32; o >= 1; o >>= 1) vv += __shfl_xor(vv, o);
        const float rs = rsqrtf(vv * (1.0f / 128.0f) + 1e-5f);
        if ((tid & 255) < 128) {
            const int idx = tid & 127;
            const float myv = (idx < 64) ? v0 : v1;
            qlnl[q][idx] = (myv - mean) * rs * g_q[idx] + be_q[idx];
        }
    }
    __syncthreads();

    // qh: half-wave-per-row GEMV, K=128 (row pair per wave; 512B/half coalesced)
    #pragma unroll 4
    for (int t = wave; t < 128; t += 8) {
        const int row = t * 2 + (lane >> 5);     // 0..255
        const int q = row >> 7, c = row & 127;
        const float4 w4 = ((const float4*)(w_in + (size_t)c * C_IN))[lane & 31];
        const float4 x4 = ((const float4*)&qlnl[q][0])[lane & 31];
        float a = dot4(w4, x4);
        a += __shfl_xor(a, 1); a += __shfl_xor(a, 2); a += __shfl_xor(a, 4);
        a += __shfl_xor(a, 8); a += __shfl_xor(a, 16);
        if ((lane & 31) == 0)
            pack[(size_t)(q ? mB : mA) * C_BEV + c] = a + b_in[c];
    }
}

// ---- attention kernel (R13 body; av projection now coalesced wave-GEMV)
__global__ __launch_bounds__(512) void k_attn(
    const float* __restrict__ vf, const int* __restrict__ spi,
    const int* __restrict__ ni, const int* __restrict__ kidx,
    float* __restrict__ pack,
    const float* __restrict__ w_pos, const float* __restrict__ b_pos,
    const float* __restrict__ g_k, const float* __restrict__ be_k,
    const float* __restrict__ w_in, const float* __restrict__ b_in,
    const int M)
{
    const int tid = threadIdx.x;
    const int m2 = blockIdx.x * 2;
    const int mA = m2;
    const int mB = (m2 + 1 < M) ? (m2 + 1) : (M - 1);

    __shared__ ushort kf16[64][C_IN + 8];
    __shared__ float qhs[2 * C_IN];
    __shared__ float tk[2 * 4 * C_IN];
    __shared__ float attnw[2 * 4 * NKEY];
    __shared__ int   kmsk[64];

    const int nxA = ni[mA*4+3], nyA = ni[mA*4+2];
    const int nxB = ni[mB*4+3], nyB = ni[mB*4+2];

    // ---- P1: 64 key rows x 8 threads (verbatim R8/R13)
    {
        const int kk = tid >> 3;
        const int qk = kk >> 5;
        const int g  = tid & 7;
        const int c0 = g * 16;
        const int mq = qk ? mB : mA;
        const int nxk = qk ? nxB : nxA, nyk = qk ? nyB : nyA;
        const float qxk = (nxk + 0.5f) * (150.4f / 180.0f) - 75.2f;
        const float qyk = (nyk + 0.5f) * (150.4f / 180.0f) - 75.2f;

        const int kv = kidx[mq * NKEY + (kk & 31)];
        if (g == 0) kmsk[kk] = (kv < 0) ? 1 : 0;
        const int safe = (kv < 0) ? 0 : kv;
        const int sz = spi[safe * 4 + 1];
        const int sy = spi[safe * 4 + 2];
        const int sx = spi[safe * 4 + 3];
        const float cx = (sx + 0.5f) * (150.4f / 1440.0f) - 75.2f - qxk;
        const float cy = (sy + 0.5f) * (150.4f / 1440.0f) - 75.2f - qyk;
        const float cz = (sz + 0.5f) * (6.0f / 40.0f)     - 2.0f  - 1.0f;

        float v[16];
        const float4* src = (const float4*)(vf + (size_t)safe * C_IN + c0);
        #pragma unroll
        for (int j = 0; j < 4; ++j) {
            float4 t = src[j];
            v[j*4+0] = t.x; v[j*4+1] = t.y; v[j*4+2] = t.z; v[j*4+3] = t.w;
        }
        #pragma unroll
        for (int j = 0; j < 16; ++j) {
            const int c = c0 + j;
            float e = cx * w_pos[c*3+0] + cy * w_pos[c*3+1] + cz * w_pos[c*3+2] + b_pos[c];
            v[j] += gelu_exact(e);
        }
        float s = 0.f;
        #pragma unroll
        for (int j = 0; j < 16; ++j) s += v[j];
        s += __shfl_xor(s, 1); s += __shfl_xor(s, 2); s += __shfl_xor(s, 4);
        const float mean = s * (1.0f / 128.0f);
        float vv = 0.f;
        #pragma unroll
        for (int j = 0; j < 16; ++j) { float d = v[j] - mean; vv += d * d; }
        vv += __shfl_xor(vv, 1); vv += __shfl_xor(vv, 2); vv += __shfl_xor(vv, 4);
        const float rs = rsqrtf(vv * (1.0f / 128.0f) + 1e-5f);
        ushort o[16];
        #pragma unroll
        for (int j = 0; j < 16; ++j) {
            const int c = c0 + j;
            o[j] = f2bf((v[j] - mean) * rs * g_k[c] + be_k[c]);
        }
        short8* drow = (short8*)(&kf16[kk][c0]);
        drow[0] = *(short8*)&o[0];
        drow[1] = *(short8*)&o[8];
    }

    // stage qh from pack[m][0:128]
    if (tid < 256) {
        const int q = tid >> 7, idx = tid & 127;
        qhs[q * 128 + idx] = pack[(size_t)(q ? mB : mA) * C_BEV + idx];
    }
    __syncthreads();

    // ---- t[h] = qh_h @ wk_h (c contiguous across lanes -> already coalesced)
    {
        const int q = tid >> 8, r = tid & 255;
        const int c = r & 127, h2 = r >> 7;
        #pragma unroll
        for (int hi = 0; hi < 2; ++hi) {
            const int hh = h2 + 2 * hi;
            float acc = 0.f;
            #pragma unroll
            for (int d = 0; d < D_H; ++d)
                acc += qhs[q*128 + hh*D_H + d] * w_in[(size_t)(C_IN + hh*D_H + d) * C_IN + c];
            tk[(q*4 + hh)*128 + c] = acc;
        }
    }
    __syncthreads();

    // ---- logits + masked softmax (unchanged)
    if (tid < 256) {
        const int q = tid >> 7, h = (tid >> 5) & 3, p = tid & 31;
        float tbv = qhs[q*128 + h*D_H + p] * b_in[C_IN + h*D_H + p];
        #pragma unroll
        for (int o = 16; o >= 1; o >>= 1) tbv += __shfl_xor(tbv, o);
        const float* tr = &tk[(q*4 + h)*128];
        const ushort* kr = kf16[q*NKEY + p];
        float d = 0.f;
        #pragma unroll
        for (int c2 = 0; c2 < 64; ++c2) {
            const uint u = *(const uint*)&kr[c2*2];
            d += tr[c2*2]   * bf2f((ushort)(u & 0xffff));
            d += tr[c2*2+1] * bf2f((ushort)(u >> 16));
        }
        const int msk = kmsk[q*NKEY + p];
        float logit = msk ? -3.0e38f : (d + tbv) * 0.17677669529663687f;
        float mx = logit;
        #pragma unroll
        for (int o = 16; o >= 1; o >>= 1) mx = fmaxf(mx, __shfl_xor(mx, o));
        const float e = msk ? 0.0f : expf(logit - mx);
        float ssum = e;
        #pragma unroll
        for (int o = 16; o >= 1; o >>= 1) ssum += __shfl_xor(ssum, o);
        attnw[(q*4 + h)*32 + p] = e / ssum;
    }
    __syncthreads();

    // ---- kbar[h] = sum_p attn[h,p] k[p] (unchanged; LDS-only)
    {
        const int q = tid >> 8, r = tid & 255;
        const int c = r & 127, h2 = r >> 7;
        #pragma unroll
        for (int hi = 0; hi < 2; ++hi) {
            const int hh = h2 + 2 * hi;
            float acc = 0.f;
            #pragma unroll
            for (int p = 0; p < NKEY; ++p)
                acc += attnw[(q*4 + hh)*32 + p] * bf2f(kf16[q*NKEY + p][c]);
            tk[(q*4 + hh)*128 + c] = acc;
        }
    }
    __syncthreads();

    // ---- av: half-wave-per-row coalesced GEMV over w_in rows [256,384)
    {
        const int wave = tid >> 6, lane = tid & 63;
        #pragma unroll 4
        for (int t = wave; t < 128; t += 8) {
            const int row = t * 2 + (lane >> 5);   // 0..255
            const int q = row >> 7, j = row & 127;
            const int h = j >> 5;
            const float4 w4 = ((const float4*)(w_in + (size_t)(2*C_IN + j) * C_IN))[lane & 31];
            const float4 k4 = ((const float4*)&tk[(q*4 + h)*128])[lane & 31];
            float a = dot4(w4, k4);
            a += __shfl_xor(a, 1); a += __shfl_xor(a, 2); a += __shfl_xor(a, 4);
            a += __shfl_xor(a, 8); a += __shfl_xor(a, 16);
            if ((lane & 31) == 0 && (m2 + q) < M)
                pack[(size_t)(q ? mB : mA) * C_BEV + C_IN + j] = a + b_in[2*C_IN + j];
        }
    }
}

// ---- fused post-attention (COALESCED wave-GEMVs):
//   xf = av @ w_out^T + b_out + sc; yln = LN(xf);
//   h1 = gelu(yln @ w_fc1^T + b_fc1); feat = h1 @ w_fc2^T + b_fc2 + xf.
__global__ __launch_bounds__(512) void k_post(
    const float* __restrict__ pack,   // av at [m][128:256]
    const float* __restrict__ w_out, const float* __restrict__ b_out,
    const float* __restrict__ g_f, const float* __restrict__ be_f,
    const float* __restrict__ w_fc1, const float* __restrict__ b_fc1,
    const float* __restrict__ w_fc2, const float* __restrict__ b_fc2,
    float* __restrict__ scfeat, const int M)
{
    __shared__ float avl[2][C_IN];
    __shared__ float sclp[2][C_IN];
    __shared__ float xfl[2][C_IN];
    __shared__ float ylnl[2][C_IN];
    __shared__ float h1l[2][C_IN];
    const int tid = threadIdx.x;
    const int mA = blockIdx.x * 2;
    const int mB = (mA + 1 < M) ? (mA + 1) : (M - 1);
    const int wave = tid >> 6, lane = tid & 63;

    // stage av and sc (coalesced)
    if (tid < 256) {
        const int q = tid >> 7, i = tid & 127;
        avl[q][i] = pack[(size_t)(q ? mB : mA) * C_BEV + C_IN + i];
    } else {
        const int t2 = tid - 256;
        const int q = t2 >> 7, i = t2 & 127;
        sclp[q][i] = scfeat[(size_t)(q ? mB : mA) * C_IN + i];
    }
    __syncthreads();

    // xf = av @ w_out^T + b_out + sc   (half-wave-per-row, K=128)
    #pragma unroll 4
    for (int t = wave; t < 128; t += 8) {
        const int row = t * 2 + (lane >> 5);
        const int q = row >> 7, c = row & 127;
        const float4 w4 = ((const float4*)(w_out + (size_t)c * C_IN))[lane & 31];
        const float4 a4 = ((const float4*)&avl[q][0])[lane & 31];
        float a = dot4(w4, a4);
        a += __shfl_xor(a, 1); a += __shfl_xor(a, 2); a += __shfl_xor(a, 4);
        a += __shfl_xor(a, 8); a += __shfl_xor(a, 16);
        if ((lane & 31) == 0) xfl[q][c] = a + b_out[c] + sclp[q][c];
    }
    __syncthreads();

    // yln = LN(xf)  (unchanged)
    {
        const int q = tid >> 8, l2 = tid & 63;
        const float v0 = xfl[q][l2], v1 = xfl[q][l2 + 64];
        float s = v0 + v1;
        #pragma unroll
        for (int o = 32; o >= 1; o >>= 1) s += __shfl_xor(s, o);
        const float mean = s * (1.0f / 128.0f);
        const float d0 = v0 - mean, d1 = v1 - mean;
        float vv = d0 * d0 + d1 * d1;
        #pragma unroll
        for (int o = 32; o >= 1; o >>= 1) vv += __shfl_xor(vv, o);
        const float rs = rsqrtf(vv * (1.0f / 128.0f) + 1e-5f);
        if ((tid & 255) < 128) {
            const int idx = tid & 127;
            const float myv = (idx < 64) ? v0 : v1;
            ylnl[q][idx] = (myv - mean) * rs * g_f[idx] + be_f[idx];
        }
    }
    __syncthreads();

    // h1 = gelu(yln @ w_fc1^T + b_fc1)   (half-wave-per-row)
    #pragma unroll 4
    for (int t = wave; t < 128; t += 8) {
        const int row = t * 2 + (lane >> 5);
        const int q = row >> 7, c = row & 127;
        const float4 w4 = ((const float4*)(w_fc1 + (size_t)c * C_IN))[lane & 31];
        const float4 y4 = ((const float4*)&ylnl[q][0])[lane & 31];
        float a = dot4(w4, y4);
        a += __shfl_xor(a, 1); a += __shfl_xor(a, 2); a += __shfl_xor(a, 4);
        a += __shfl_xor(a, 8); a += __shfl_xor(a, 16);
        if ((lane & 31) == 0) h1l[q][c] = gelu_exact(a + b_fc1[c]);
    }
    __syncthreads();

    // feat = h1 @ w_fc2^T + b_fc2 + xf -> scfeat in-place (half-wave-per-row)
    #pragma unroll 4
    for (int t = wave; t < 128; t += 8) {
        const int row = t * 2 + (lane >> 5);
        const int q = row >> 7, c = row & 127;
        const float4 w4 = ((const float4*)(w_fc2 + (size_t)c * C_IN))[lane & 31];
        const float4 h4 = ((const float4*)&h1l[q][0])[lane & 31];
        float a = dot4(w4, h4);
        a += __shfl_xor(a, 1); a += __shfl_xor(a, 2); a += __shfl_xor(a, 4);
        a += __shfl_xor(a, 8); a += __shfl_xor(a, 16);
        if ((lane & 31) == 0 && (mA + q) < M)
            scfeat[(size_t)(q ? mB : mA) * C_IN + c] = a + b_fc2[c] + xfl[q][c];
    }
}

extern "C" void kernel_launch(void* const* d_in, const int* in_sizes, int n_in,
                              void* d_out, int out_size, void* d_ws, size_t ws_size,
                              hipStream_t stream) {
    const float* vf    = (const float*)d_in[0];
    const int*   spi   = (const int*)  d_in[1];
    const int*   ni    = (const int*)  d_in[2];
    const int*   kidx  = (const int*)  d_in[3];
    const float* bev   = (const float*)d_in[4];
    const float* w_pos = (const float*)d_in[5];
    const float* b_pos = (const float*)d_in[6];
    const float* w_bev = (const float*)d_in[7];
    const float* b_bev = (const float*)d_in[8];
    const float* g_q   = (const float*)d_in[9];
    const float* be_q  = (const float*)d_in[10];
    const float* g_k   = (const float*)d_in[11];
    const float* be_k  = (const float*)d_in[12];
    const float* g_f   = (const float*)d_in[13];
    const float* be_f  = (const float*)d_in[14];
    const float* w_in  = (const float*)d_in[15];
    const float* b_in  = (const float*)d_in[16];
    const float* w_out = (const float*)d_in[17];
    const float* b_out = (const float*)d_in[18];
    const float* w_fc1 = (const float*)d_in[19];
    const float* b_fc1 = (const float*)d_in[20];
    const float* w_fc2 = (const float*)d_in[21];
    const float* b_fc2 = (const float*)d_in[22];
    float* out = (float*)d_out;

    const int M = in_sizes[3] / NKEY;
    const int npairs = (M + 1) / 2;

    // ---- workspace:
    //  inv    @0      (1.98 MiB)
    //  pack   @2MiB   [M][256] f32: bevq -> row[0:128]=qh, row[128:256]=av
    //  scfeat @32MiB  [M][128] f32: sc, then featbuf in-place
    char* ws = (char*)d_ws;
    const size_t MiB = 1u << 20;
    int*   inv    = (int*)ws;
    float* pack   = (float*)(ws + 2 * MiB);
    float* scfeat = (float*)(ws + 32 * MiB);

    hipMemsetAsync(inv, 0xFF, (size_t)4 * H_Y * W_X * sizeof(int), stream);
    build_inv<<<(M + 255) / 256, 256, 0, stream>>>(ni, inv, M);
    compact_bev<<<4 * H_Y * 12, 256, 0, stream>>>(bev, inv, pack);

    k_pre<<<npairs, 512, 0, stream>>>(pack, w_bev, b_bev, g_q, be_q, w_in, b_in, scfeat, M);
    k_attn<<<npairs, 512, 0, stream>>>(vf, spi, ni, kidx, pack, w_pos, b_pos,
                                       g_k, be_k, w_in, b_in, M);
    k_post<<<npairs, 512, 0, stream>>>(pack, w_out, b_out, g_f, be_f,
                                       w_fc1, b_fc1, w_fc2, b_fc2, scfeat, M);

    write_out<<<2048, 256, 0, stream>>>(inv, scfeat, out);
}